// Round 1
// baseline (877.308 us; speedup 1.0000x reference)
//
#include <hip/hip_runtime.h>
#include <hip/hip_bf16.h>
#include <stdint.h>

// RWKV4 time-mix for B=4, T=2048, H=2048 on gfx950.
#define B_ 4
#define T_ 2048
#define H_ 2048
#define BT_ (B_ * T_)

typedef __bf16 bf16x8 __attribute__((ext_vector_type(8)));
typedef float f32x4 __attribute__((ext_vector_type(4)));

// async global->LDS, 16B per lane. LDS dest is wave-uniform base + lane*16.
__device__ inline void async16(const void* g, void* l) {
  __builtin_amdgcn_global_load_lds(
      (__attribute__((address_space(1))) uint32_t*)(void*)(uintptr_t)g,
      (__attribute__((address_space(3))) uint32_t*)l,
      16, 0, 0);
}

// ---------------------------------------------------------------- f32 -> bf16
__global__ __launch_bounds__(256) void cvt_bf16_kernel(
    const float* __restrict__ src, __bf16* __restrict__ dst) {
  int i = (blockIdx.x * 256 + threadIdx.x) * 8;
  const float4* s4 = (const float4*)(src + i);
  float4 a = s4[0], b = s4[1];
  bf16x8 o;
  o[0] = (__bf16)a.x; o[1] = (__bf16)a.y; o[2] = (__bf16)a.z; o[3] = (__bf16)a.w;
  o[4] = (__bf16)b.x; o[5] = (__bf16)b.y; o[6] = (__bf16)b.z; o[7] = (__bf16)b.w;
  *(bf16x8*)(dst + i) = o;
}

// ------------------------------------------------- LayerNorm + token-shift mix
// One block per (b,t) row. Recomputes LN of row t-1 for the shifted input.
__global__ __launch_bounds__(256) void ln_mix_kernel(
    const float* __restrict__ h, const float* __restrict__ lnw,
    const float* __restrict__ lnb, const float* __restrict__ mk,
    const float* __restrict__ mv, const float* __restrict__ mr,
    __bf16* __restrict__ xk, __bf16* __restrict__ xv, __bf16* __restrict__ xr,
    float* __restrict__ xlast) {
  const int row = blockIdx.x;          // b*T + t
  const int t = row & (T_ - 1);
  const int tid = threadIdx.x;
  const bool hasprev = (t != 0);

  const float4* cr = (const float4*)(h + (size_t)row * H_);
  float4 c0 = cr[tid * 2 + 0], c1 = cr[tid * 2 + 1];
  float4 p0 = {0.f, 0.f, 0.f, 0.f}, p1 = {0.f, 0.f, 0.f, 0.f};
  if (hasprev) {
    const float4* pr = (const float4*)(h + (size_t)(row - 1) * H_);
    p0 = pr[tid * 2 + 0]; p1 = pr[tid * 2 + 1];
  }
  float4 red;
  red.x = c0.x + c0.y + c0.z + c0.w + c1.x + c1.y + c1.z + c1.w;
  red.y = c0.x * c0.x + c0.y * c0.y + c0.z * c0.z + c0.w * c0.w +
          c1.x * c1.x + c1.y * c1.y + c1.z * c1.z + c1.w * c1.w;
  red.z = p0.x + p0.y + p0.z + p0.w + p1.x + p1.y + p1.z + p1.w;
  red.w = p0.x * p0.x + p0.y * p0.y + p0.z * p0.z + p0.w * p0.w +
          p1.x * p1.x + p1.y * p1.y + p1.z * p1.z + p1.w * p1.w;
  #pragma unroll
  for (int off = 32; off; off >>= 1) {
    red.x += __shfl_down(red.x, off);
    red.y += __shfl_down(red.y, off);
    red.z += __shfl_down(red.z, off);
    red.w += __shfl_down(red.w, off);
  }
  __shared__ float4 rbuf[4];
  const int lane = tid & 63, wid = tid >> 6;
  if (lane == 0) rbuf[wid] = red;
  __syncthreads();
  float4 tot;
  tot.x = rbuf[0].x + rbuf[1].x + rbuf[2].x + rbuf[3].x;
  tot.y = rbuf[0].y + rbuf[1].y + rbuf[2].y + rbuf[3].y;
  tot.z = rbuf[0].z + rbuf[1].z + rbuf[2].z + rbuf[3].z;
  tot.w = rbuf[0].w + rbuf[1].w + rbuf[2].w + rbuf[3].w;

  const float inv = 1.0f / (float)H_;
  float mu = tot.x * inv;
  float rstd = rsqrtf(fmaxf(tot.y * inv - mu * mu, 0.f) + 1e-5f);
  float mup = tot.z * inv;
  float rstdp = rsqrtf(fmaxf(tot.w * inv - mup * mup, 0.f) + 1e-5f);

  float xc[8] = {c0.x, c0.y, c0.z, c0.w, c1.x, c1.y, c1.z, c1.w};
  float xp[8] = {p0.x, p0.y, p0.z, p0.w, p1.x, p1.y, p1.z, p1.w};
  const float4* W4 = (const float4*)lnw;
  const float4* Bv4 = (const float4*)lnb;
  const float4* MK4 = (const float4*)mk;
  const float4* MV4 = (const float4*)mv;
  const float4* MR4 = (const float4*)mr;
  float4 w0 = W4[tid * 2], w1 = W4[tid * 2 + 1];
  float4 b0 = Bv4[tid * 2], b1 = Bv4[tid * 2 + 1];
  float4 k0 = MK4[tid * 2], k1 = MK4[tid * 2 + 1];
  float4 v0 = MV4[tid * 2], v1 = MV4[tid * 2 + 1];
  float4 r0 = MR4[tid * 2], r1 = MR4[tid * 2 + 1];
  float wa[8] = {w0.x, w0.y, w0.z, w0.w, w1.x, w1.y, w1.z, w1.w};
  float ba[8] = {b0.x, b0.y, b0.z, b0.w, b1.x, b1.y, b1.z, b1.w};
  float ka[8] = {k0.x, k0.y, k0.z, k0.w, k1.x, k1.y, k1.z, k1.w};
  float va[8] = {v0.x, v0.y, v0.z, v0.w, v1.x, v1.y, v1.z, v1.w};
  float ra[8] = {r0.x, r0.y, r0.z, r0.w, r1.x, r1.y, r1.z, r1.w};

  bf16x8 ok_, ov_, or_;
  float xls[8];
  #pragma unroll
  for (int e = 0; e < 8; e++) {
    float x = (xc[e] - mu) * rstd * wa[e] + ba[e];
    float sx = hasprev ? (xp[e] - mup) * rstdp * wa[e] + ba[e] : 0.f;
    ok_[e] = (__bf16)(sx + ka[e] * (x - sx));
    ov_[e] = (__bf16)(sx + va[e] * (x - sx));
    or_[e] = (__bf16)(sx + ra[e] * (x - sx));
    xls[e] = x;
  }
  size_t obase = (size_t)row * H_ + tid * 8;
  *(bf16x8*)(xk + obase) = ok_;
  *(bf16x8*)(xv + obase) = ov_;
  *(bf16x8*)(xr + obase) = or_;
  if (t == T_ - 1) {
    float* dst = xlast + (size_t)(row >> 11) * H_ + tid * 8;
    #pragma unroll
    for (int e = 0; e < 8; e++) dst[e] = xls[e];
  }
}

// --------------------------------------------------------- bf16 NT GEMM (m97)
// C[m][o] = sum_h A[m][h] * W[o][h].  128x128 tile, BK=32, 4 waves (2x2),
// each wave 64x64 = 4x4 fragments of 16x16x32 MFMA.
// MODE 0: store f32. MODE 1: sigmoid -> bf16. MODE 2: residual add -> f32.
template <int MODE>
__global__ __launch_bounds__(256) void gemm_nt(
    const __bf16* __restrict__ A, const __bf16* __restrict__ Bw,
    float* __restrict__ outf, __bf16* __restrict__ outb,
    const float* __restrict__ resid) {
  __shared__ __align__(16) __bf16 lds_a[128 * 32];
  __shared__ __align__(16) __bf16 lds_b[128 * 32];
  const int bn = blockIdx.x, bm = blockIdx.y;
  const int tid = threadIdx.x;
  const int lane = tid & 63, wv = tid >> 6;
  const int wr = wv >> 1, wc = wv & 1;
  const int q = lane >> 4, rr = lane & 15;

  f32x4 acc[4][4];
  #pragma unroll
  for (int m = 0; m < 4; m++)
    #pragma unroll
    for (int n = 0; n < 4; n++) acc[m][n] = (f32x4){0.f, 0.f, 0.f, 0.f};

  const char* Ab = (const char*)(A + (size_t)bm * 128 * H_);
  const char* Bb = (const char*)(Bw + (size_t)bn * 128 * H_);
  const int li0 = wv * 1024 + lane * 16;

  for (int k0 = 0; k0 < H_; k0 += 32) {
    #pragma unroll
    for (int j = 0; j < 2; j++) {
      int li = j * 4096 + li0;
      int rowi = li >> 6, cb = li & 63;
      size_t goff = (size_t)rowi * (H_ * 2) + (k0 << 1) + cb;
      async16(Ab + goff, (char*)lds_a + j * 4096 + wv * 1024);
      async16(Bb + goff, (char*)lds_b + j * 4096 + wv * 1024);
    }
    __syncthreads();
    bf16x8 af[4], bf[4];
    #pragma unroll
    for (int m = 0; m < 4; m++)
      af[m] = *(const bf16x8*)(lds_a + ((wr * 64 + m * 16 + rr) << 5) + (q << 3));
    #pragma unroll
    for (int n = 0; n < 4; n++)
      bf[n] = *(const bf16x8*)(lds_b + ((wc * 64 + n * 16 + rr) << 5) + (q << 3));
    #pragma unroll
    for (int m = 0; m < 4; m++)
      #pragma unroll
      for (int n = 0; n < 4; n++)
        acc[m][n] = __builtin_amdgcn_mfma_f32_16x16x32_bf16(af[m], bf[n], acc[m][n], 0, 0, 0);
    __syncthreads();
  }

  const int r0 = bm * 128 + wr * 64 + (q << 2);
  const int c0 = bn * 128 + wc * 64 + rr;
  #pragma unroll
  for (int m = 0; m < 4; m++) {
    #pragma unroll
    for (int n = 0; n < 4; n++) {
      int col = c0 + n * 16;
      #pragma unroll
      for (int rg = 0; rg < 4; rg++) {
        int rowg = r0 + m * 16 + rg;
        size_t idx = (size_t)rowg * H_ + col;
        float vv = acc[m][n][rg];
        if (MODE == 0) {
          outf[idx] = vv;
        } else if (MODE == 1) {
          outb[idx] = (__bf16)(1.f / (1.f + __expf(-vv)));
        } else {
          outf[idx] = resid[idx] + vv;
        }
      }
    }
  }
}

// -------------------------------------------------------------- WKV recurrence
// One thread per (b,h) channel; serial over T with 16-deep batched loads.
__global__ __launch_bounds__(256) void wkv_kernel(
    const float* __restrict__ k, const float* __restrict__ v,
    const __bf16* __restrict__ r, const float* __restrict__ td,
    const float* __restrict__ cw, __bf16* __restrict__ a,
    float* __restrict__ ndn /* -> num[B*H], den[B*H], norm[B*H] */) {
  const int id = blockIdx.x * 256 + threadIdx.x;  // 0..B*H-1
  const int b = id >> 11;
  const int hh = id & (H_ - 1);
  const float decay = -__expf(td[hh]);
  const float cwv = cw[hh];
  float num = 0.f, den = 0.f, norm = -INFINITY;

  const int UN = 16;
  for (int t0 = 0; t0 < T_; t0 += UN) {
    float kk[UN], vv[UN], rr[UN];
    size_t base = ((size_t)b * T_ + t0) * H_ + hh;
    #pragma unroll
    for (int i = 0; i < UN; i++) {
      kk[i] = k[base + (size_t)i * H_];
      vv[i] = v[base + (size_t)i * H_];
      rr[i] = (float)r[base + (size_t)i * H_];
    }
    #pragma unroll
    for (int i = 0; i < UN; i++) {
      float kt = kk[i], vt = vv[i];
      float ct = cwv + kt;
      float cn = fmaxf(ct, norm);
      float ep = __expf(norm - cn), ec = __expf(ct - cn);
      float o = (ep * num + ec * vt) / (ep * den + ec);
      a[base + (size_t)i * H_] = (__bf16)(rr[i] * o);
      float dpn = decay + norm;
      float nn = fmaxf(dpn, kt);
      float ed = __expf(dpn - nn), ek = __expf(kt - nn);
      num = ed * num + ek * vt;
      den = ed * den + ek;
      norm = nn;
    }
  }
  ndn[id] = num;
  ndn[B_ * H_ + id] = den;
  ndn[2 * B_ * H_ + id] = norm;
}

// ----------------------------------------------------------------------- host
extern "C" void kernel_launch(void* const* d_in, const int* in_sizes, int n_in,
                              void* d_out, int out_size, void* d_ws, size_t ws_size,
                              hipStream_t stream) {
  const float* h   = (const float*)d_in[0];
  const float* lnw = (const float*)d_in[1];
  const float* lnb = (const float*)d_in[2];
  const float* Wk  = (const float*)d_in[3];
  const float* Wv  = (const float*)d_in[4];
  const float* Wr  = (const float*)d_in[5];
  const float* Wo  = (const float*)d_in[6];
  const float* mk  = (const float*)d_in[7];
  const float* mv  = (const float*)d_in[8];
  const float* mr  = (const float*)d_in[9];
  const float* td  = (const float*)d_in[10];
  const float* cw  = (const float*)d_in[11];

  char* ws = (char*)d_ws;
  const size_t MB32 = 33554432;
  __bf16* xk   = (__bf16*)(ws);              // later reused as 'a' (r*wkv)
  __bf16* xv   = (__bf16*)(ws + MB32);       // later reused as 'r'
  __bf16* xr   = (__bf16*)(ws + 2 * MB32);
  float*  kbuf = (float*)(ws + 3 * MB32);    // 64 MB
  float*  vbuf = (float*)(ws + 3 * MB32 + 67108864);
  __bf16* Wk16 = (__bf16*)(ws + 3 * MB32 + 2 * 67108864);
  __bf16* Wv16 = Wk16 + (size_t)H_ * H_;
  __bf16* Wr16 = Wv16 + (size_t)H_ * H_;
  __bf16* Wo16 = Wr16 + (size_t)H_ * H_;

  float* out  = (float*)d_out;
  float* xlast = out + (size_t)BT_ * H_;
  float* ndn   = xlast + (size_t)B_ * H_;

  const int cvt_blocks = (H_ * H_) / (256 * 8);
  cvt_bf16_kernel<<<cvt_blocks, 256, 0, stream>>>(Wk, Wk16);
  cvt_bf16_kernel<<<cvt_blocks, 256, 0, stream>>>(Wv, Wv16);
  cvt_bf16_kernel<<<cvt_blocks, 256, 0, stream>>>(Wr, Wr16);
  cvt_bf16_kernel<<<cvt_blocks, 256, 0, stream>>>(Wo, Wo16);

  ln_mix_kernel<<<BT_, 256, 0, stream>>>(h, lnw, lnb, mk, mv, mr, xk, xv, xr, xlast);

  dim3 gg(H_ / 128, BT_ / 128);
  gemm_nt<0><<<gg, 256, 0, stream>>>(xk, Wk16, kbuf, nullptr, nullptr);
  gemm_nt<0><<<gg, 256, 0, stream>>>(xv, Wv16, vbuf, nullptr, nullptr);
  gemm_nt<1><<<gg, 256, 0, stream>>>(xr, Wr16, nullptr, xv /* r reuses xv */, nullptr);

  wkv_kernel<<<(B_ * H_) / 256, 256, 0, stream>>>(kbuf, vbuf, xv, td, cw,
                                                  xk /* a reuses xk */, ndn);

  gemm_nt<2><<<gg, 256, 0, stream>>>(xk, Wo16, out, nullptr, h);
}

// Round 3
// 584.927 us; speedup vs baseline: 1.4999x; 1.4999x over previous
//
#include <hip/hip_runtime.h>
#include <hip/hip_bf16.h>
#include <stdint.h>

// RWKV4 time-mix for B=4, T=2048, H=2048 on gfx950.
#define B_ 4
#define T_ 2048
#define H_ 2048
#define BT_ (B_ * T_)
#define BH_ (B_ * H_)
#define CH_ 32              // number of time chunks for the WKV scan
#define CL_ (T_ / CH_)      // chunk length = 64

typedef __bf16 bf16x8 __attribute__((ext_vector_type(8)));
typedef float f32x4 __attribute__((ext_vector_type(4)));

// async global->LDS, 16B per lane. LDS dest is wave-uniform base + lane*16.
__device__ inline void async16(const void* g, void* l) {
  __builtin_amdgcn_global_load_lds(
      (__attribute__((address_space(1))) uint32_t*)(void*)(uintptr_t)g,
      (__attribute__((address_space(3))) uint32_t*)l,
      16, 0, 0);
}

// ---------------------------------------------------------------- f32 -> bf16
__global__ __launch_bounds__(256) void cvt_bf16_kernel(
    const float* __restrict__ src, __bf16* __restrict__ dst) {
  int i = (blockIdx.x * 256 + threadIdx.x) * 8;
  const float4* s4 = (const float4*)(src + i);
  float4 a = s4[0], b = s4[1];
  bf16x8 o;
  o[0] = (__bf16)a.x; o[1] = (__bf16)a.y; o[2] = (__bf16)a.z; o[3] = (__bf16)a.w;
  o[4] = (__bf16)b.x; o[5] = (__bf16)b.y; o[6] = (__bf16)b.z; o[7] = (__bf16)b.w;
  *(bf16x8*)(dst + i) = o;
}

// ------------------------------------------------- LayerNorm + token-shift mix
__global__ __launch_bounds__(256) void ln_mix_kernel(
    const float* __restrict__ h, const float* __restrict__ lnw,
    const float* __restrict__ lnb, const float* __restrict__ mk,
    const float* __restrict__ mv, const float* __restrict__ mr,
    __bf16* __restrict__ xk, __bf16* __restrict__ xv, __bf16* __restrict__ xr,
    float* __restrict__ xlast) {
  const int row = blockIdx.x;          // b*T + t
  const int t = row & (T_ - 1);
  const int tid = threadIdx.x;
  const bool hasprev = (t != 0);

  const float4* cr = (const float4*)(h + (size_t)row * H_);
  float4 c0 = cr[tid * 2 + 0], c1 = cr[tid * 2 + 1];
  float4 p0 = {0.f, 0.f, 0.f, 0.f}, p1 = {0.f, 0.f, 0.f, 0.f};
  if (hasprev) {
    const float4* pr = (const float4*)(h + (size_t)(row - 1) * H_);
    p0 = pr[tid * 2 + 0]; p1 = pr[tid * 2 + 1];
  }
  float4 red;
  red.x = c0.x + c0.y + c0.z + c0.w + c1.x + c1.y + c1.z + c1.w;
  red.y = c0.x * c0.x + c0.y * c0.y + c0.z * c0.z + c0.w * c0.w +
          c1.x * c1.x + c1.y * c1.y + c1.z * c1.z + c1.w * c1.w;
  red.z = p0.x + p0.y + p0.z + p0.w + p1.x + p1.y + p1.z + p1.w;
  red.w = p0.x * p0.x + p0.y * p0.y + p0.z * p0.z + p0.w * p0.w +
          p1.x * p1.x + p1.y * p1.y + p1.z * p1.z + p1.w * p1.w;
  #pragma unroll
  for (int off = 32; off; off >>= 1) {
    red.x += __shfl_down(red.x, off);
    red.y += __shfl_down(red.y, off);
    red.z += __shfl_down(red.z, off);
    red.w += __shfl_down(red.w, off);
  }
  __shared__ float4 rbuf[4];
  const int lane = tid & 63, wid = tid >> 6;
  if (lane == 0) rbuf[wid] = red;
  __syncthreads();
  float4 tot;
  tot.x = rbuf[0].x + rbuf[1].x + rbuf[2].x + rbuf[3].x;
  tot.y = rbuf[0].y + rbuf[1].y + rbuf[2].y + rbuf[3].y;
  tot.z = rbuf[0].z + rbuf[1].z + rbuf[2].z + rbuf[3].z;
  tot.w = rbuf[0].w + rbuf[1].w + rbuf[2].w + rbuf[3].w;

  const float inv = 1.0f / (float)H_;
  float mu = tot.x * inv;
  float rstd = rsqrtf(fmaxf(tot.y * inv - mu * mu, 0.f) + 1e-5f);
  float mup = tot.z * inv;
  float rstdp = rsqrtf(fmaxf(tot.w * inv - mup * mup, 0.f) + 1e-5f);

  float xc[8] = {c0.x, c0.y, c0.z, c0.w, c1.x, c1.y, c1.z, c1.w};
  float xp[8] = {p0.x, p0.y, p0.z, p0.w, p1.x, p1.y, p1.z, p1.w};
  const float4* W4 = (const float4*)lnw;
  const float4* Bv4 = (const float4*)lnb;
  const float4* MK4 = (const float4*)mk;
  const float4* MV4 = (const float4*)mv;
  const float4* MR4 = (const float4*)mr;
  float4 w0 = W4[tid * 2], w1 = W4[tid * 2 + 1];
  float4 b0 = Bv4[tid * 2], b1 = Bv4[tid * 2 + 1];
  float4 k0 = MK4[tid * 2], k1 = MK4[tid * 2 + 1];
  float4 v0 = MV4[tid * 2], v1 = MV4[tid * 2 + 1];
  float4 r0 = MR4[tid * 2], r1 = MR4[tid * 2 + 1];
  float wa[8] = {w0.x, w0.y, w0.z, w0.w, w1.x, w1.y, w1.z, w1.w};
  float ba[8] = {b0.x, b0.y, b0.z, b0.w, b1.x, b1.y, b1.z, b1.w};
  float ka[8] = {k0.x, k0.y, k0.z, k0.w, k1.x, k1.y, k1.z, k1.w};
  float va[8] = {v0.x, v0.y, v0.z, v0.w, v1.x, v1.y, v1.z, v1.w};
  float ra[8] = {r0.x, r0.y, r0.z, r0.w, r1.x, r1.y, r1.z, r1.w};

  bf16x8 ok_, ov_, or_;
  float xls[8];
  #pragma unroll
  for (int e = 0; e < 8; e++) {
    float x = (xc[e] - mu) * rstd * wa[e] + ba[e];
    float sx = hasprev ? (xp[e] - mup) * rstdp * wa[e] + ba[e] : 0.f;
    ok_[e] = (__bf16)(sx + ka[e] * (x - sx));
    ov_[e] = (__bf16)(sx + va[e] * (x - sx));
    or_[e] = (__bf16)(sx + ra[e] * (x - sx));
    xls[e] = x;
  }
  size_t obase = (size_t)row * H_ + tid * 8;
  *(bf16x8*)(xk + obase) = ok_;
  *(bf16x8*)(xv + obase) = ov_;
  *(bf16x8*)(xr + obase) = or_;
  if (t == T_ - 1) {
    float* dst = xlast + (size_t)(row >> 11) * H_ + tid * 8;
    #pragma unroll
    for (int e = 0; e < 8; e++) dst[e] = xls[e];
  }
}

// --------------------------------------------------------- bf16 NT GEMM (m97)
template <int MODE>
__global__ __launch_bounds__(256) void gemm_nt(
    const __bf16* __restrict__ A, const __bf16* __restrict__ Bw,
    float* __restrict__ outf, __bf16* __restrict__ outb,
    const float* __restrict__ resid) {
  __shared__ __align__(16) __bf16 lds_a[128 * 32];
  __shared__ __align__(16) __bf16 lds_b[128 * 32];
  const int bn = blockIdx.x, bm = blockIdx.y;
  const int tid = threadIdx.x;
  const int lane = tid & 63, wv = tid >> 6;
  const int wr = wv >> 1, wc = wv & 1;
  const int q = lane >> 4, rr = lane & 15;

  f32x4 acc[4][4];
  #pragma unroll
  for (int m = 0; m < 4; m++)
    #pragma unroll
    for (int n = 0; n < 4; n++) acc[m][n] = (f32x4){0.f, 0.f, 0.f, 0.f};

  const char* Ab = (const char*)(A + (size_t)bm * 128 * H_);
  const char* Bb = (const char*)(Bw + (size_t)bn * 128 * H_);
  const int li0 = wv * 1024 + lane * 16;

  for (int k0 = 0; k0 < H_; k0 += 32) {
    #pragma unroll
    for (int j = 0; j < 2; j++) {
      int li = j * 4096 + li0;
      int rowi = li >> 6, cb = li & 63;
      size_t goff = (size_t)rowi * (H_ * 2) + (k0 << 1) + cb;
      async16(Ab + goff, (char*)lds_a + j * 4096 + wv * 1024);
      async16(Bb + goff, (char*)lds_b + j * 4096 + wv * 1024);
    }
    __syncthreads();
    bf16x8 af[4], bf[4];
    #pragma unroll
    for (int m = 0; m < 4; m++)
      af[m] = *(const bf16x8*)(lds_a + ((wr * 64 + m * 16 + rr) << 5) + (q << 3));
    #pragma unroll
    for (int n = 0; n < 4; n++)
      bf[n] = *(const bf16x8*)(lds_b + ((wc * 64 + n * 16 + rr) << 5) + (q << 3));
    #pragma unroll
    for (int m = 0; m < 4; m++)
      #pragma unroll
      for (int n = 0; n < 4; n++)
        acc[m][n] = __builtin_amdgcn_mfma_f32_16x16x32_bf16(af[m], bf[n], acc[m][n], 0, 0, 0);
    __syncthreads();
  }

  const int r0 = bm * 128 + wr * 64 + (q << 2);
  const int c0 = bn * 128 + wc * 64 + rr;
  #pragma unroll
  for (int m = 0; m < 4; m++) {
    #pragma unroll
    for (int n = 0; n < 4; n++) {
      int col = c0 + n * 16;
      #pragma unroll
      for (int rg = 0; rg < 4; rg++) {
        int rowg = r0 + m * 16 + rg;
        size_t idx = (size_t)rowg * H_ + col;
        float vv = acc[m][n][rg];
        if (MODE == 0) {
          outf[idx] = vv;
        } else if (MODE == 1) {
          outb[idx] = (__bf16)(1.f / (1.f + __expf(-vv)));
        } else {
          outf[idx] = resid[idx] + vv;
        }
      }
    }
  }
}

// ------------------------------------------------- WKV chunked scan (3 passes)
// pass1: per (b,h,chunk) compute chunk-local state (num,den,norm) from zero.
__global__ __launch_bounds__(256) void wkv_pass1(
    const float* __restrict__ k, const float* __restrict__ v,
    const float* __restrict__ td,
    float* __restrict__ cs_num, float* __restrict__ cs_den,
    float* __restrict__ cs_norm) {
  const int id = blockIdx.x * 256 + threadIdx.x;  // 0..B*H-1
  const int c = blockIdx.y;                       // chunk
  const int b = id >> 11;
  const int hh = id & (H_ - 1);
  const float decay = -__expf(td[hh]);
  float num = 0.f, den = 0.f, norm = -INFINITY;

  const int UN = 16;
  for (int t0 = c * CL_; t0 < (c + 1) * CL_; t0 += UN) {
    float kk[UN], vv[UN];
    size_t base = ((size_t)b * T_ + t0) * H_ + hh;
    #pragma unroll
    for (int i = 0; i < UN; i++) {
      kk[i] = k[base + (size_t)i * H_];
      vv[i] = v[base + (size_t)i * H_];
    }
    #pragma unroll
    for (int i = 0; i < UN; i++) {
      float dpn = decay + norm;
      float nn = fmaxf(dpn, kk[i]);
      float ed = __expf(dpn - nn), ek = __expf(kk[i] - nn);
      num = ed * num + ek * vv[i];
      den = ed * den + ek;
      norm = nn;
    }
  }
  cs_num[c * BH_ + id] = num;
  cs_den[c * BH_ + id] = den;
  cs_norm[c * BH_ + id] = norm;
}

// scan: per (b,h) exclusive scan over the CH_ chunk states.
__global__ __launch_bounds__(256) void wkv_scan(
    const float* __restrict__ cs_num, const float* __restrict__ cs_den,
    const float* __restrict__ cs_norm, const float* __restrict__ td,
    float* __restrict__ px_num, float* __restrict__ px_den,
    float* __restrict__ px_norm) {
  const int id = blockIdx.x * 256 + threadIdx.x;  // 0..B*H-1
  const int hh = id & (H_ - 1);
  const float Lw = -__expf(td[hh]) * (float)CL_;  // CL_ * decay
  float num = 0.f, den = 0.f, norm = -INFINITY;
  for (int c = 0; c < CH_; c++) {
    px_num[c * BH_ + id] = num;
    px_den[c * BH_ + id] = den;
    px_norm[c * BH_ + id] = norm;
    float n_c = cs_num[c * BH_ + id];
    float d_c = cs_den[c * BH_ + id];
    float m_c = cs_norm[c * BH_ + id];
    float sn = norm + Lw;                 // shifted incoming norm
    float on = fmaxf(sn, m_c);            // m_c is always finite
    float ea = __expf(sn - on), eb = __expf(m_c - on);
    num = ea * num + eb * n_c;
    den = ea * den + eb * d_c;
    norm = on;
  }
}

// pass2: per (b,h,chunk) replay the chunk from the exclusive prefix state,
// writing a = r * wkv; the last chunk writes num/den/norm outputs.
__global__ __launch_bounds__(256) void wkv_pass2(
    const float* __restrict__ k, const float* __restrict__ v,
    const __bf16* __restrict__ r, const float* __restrict__ td,
    const float* __restrict__ cw,
    const float* __restrict__ px_num, const float* __restrict__ px_den,
    const float* __restrict__ px_norm,
    __bf16* __restrict__ a, float* __restrict__ ndn) {
  const int id = blockIdx.x * 256 + threadIdx.x;  // 0..B*H-1
  const int c = blockIdx.y;
  const int b = id >> 11;
  const int hh = id & (H_ - 1);
  const float decay = -__expf(td[hh]);
  const float cwv = cw[hh];
  float num = px_num[c * BH_ + id];
  float den = px_den[c * BH_ + id];
  float norm = px_norm[c * BH_ + id];

  const int UN = 16;
  for (int t0 = c * CL_; t0 < (c + 1) * CL_; t0 += UN) {
    float kk[UN], vv[UN], rr[UN];
    size_t base = ((size_t)b * T_ + t0) * H_ + hh;
    #pragma unroll
    for (int i = 0; i < UN; i++) {
      kk[i] = k[base + (size_t)i * H_];
      vv[i] = v[base + (size_t)i * H_];
      rr[i] = (float)r[base + (size_t)i * H_];
    }
    #pragma unroll
    for (int i = 0; i < UN; i++) {
      float kt = kk[i], vt = vv[i];
      float ct = cwv + kt;
      float cn = fmaxf(ct, norm);
      float ep = __expf(norm - cn), ec = __expf(ct - cn);
      float o = (ep * num + ec * vt) / (ep * den + ec);
      a[base + (size_t)i * H_] = (__bf16)(rr[i] * o);
      float dpn = decay + norm;
      float nn = fmaxf(dpn, kt);
      float ed = __expf(dpn - nn), ek = __expf(kt - nn);
      num = ed * num + ek * vt;
      den = ed * den + ek;
      norm = nn;
    }
  }
  if (c == CH_ - 1) {
    ndn[id] = num;
    ndn[BH_ + id] = den;
    ndn[2 * BH_ + id] = norm;
  }
}

// ----------------------------------------------------------------------- host
extern "C" void kernel_launch(void* const* d_in, const int* in_sizes, int n_in,
                              void* d_out, int out_size, void* d_ws, size_t ws_size,
                              hipStream_t stream) {
  const float* h   = (const float*)d_in[0];
  const float* lnw = (const float*)d_in[1];
  const float* lnb = (const float*)d_in[2];
  const float* Wk  = (const float*)d_in[3];
  const float* Wv  = (const float*)d_in[4];
  const float* Wr  = (const float*)d_in[5];
  const float* Wo  = (const float*)d_in[6];
  const float* mk  = (const float*)d_in[7];
  const float* mv  = (const float*)d_in[8];
  const float* mr  = (const float*)d_in[9];
  const float* td  = (const float*)d_in[10];
  const float* cw  = (const float*)d_in[11];

  char* ws = (char*)d_ws;
  const size_t MB = 1048576;
  // Workspace budget is 256 MB (R2 overflowed it). Layout:
  //   [0,32)    xk   (bf16, later reused as 'a' = r*wkv)
  //   [32,64)   xv   (bf16, later reused as 'r')
  //   [64,96)   xr   (bf16; dead after gemm r -> scan state lives here)
  //   [96,160)  kbuf (f32)
  //   [160,224) vbuf (f32)
  //   [224,256) Wk16/Wv16/Wr16/Wo16 (bf16, 8 MB each)
  __bf16* xk   = (__bf16*)(ws);
  __bf16* xv   = (__bf16*)(ws + 32 * MB);
  __bf16* xr   = (__bf16*)(ws + 64 * MB);
  float*  kbuf = (float*)(ws + 96 * MB);
  float*  vbuf = (float*)(ws + 160 * MB);
  __bf16* Wk16 = (__bf16*)(ws + 224 * MB);
  __bf16* Wv16 = Wk16 + (size_t)H_ * H_;
  __bf16* Wr16 = Wv16 + (size_t)H_ * H_;
  __bf16* Wo16 = Wr16 + (size_t)H_ * H_;
  // Scan state (6 x 1 MB) overlays xr's region: written only after the
  // r-GEMM (the last reader of xr) has completed in stream order.
  float* cs_num  = (float*)(ws + 64 * MB);
  float* cs_den  = cs_num + (size_t)CH_ * BH_;
  float* cs_norm = cs_den + (size_t)CH_ * BH_;
  float* px_num  = cs_norm + (size_t)CH_ * BH_;
  float* px_den  = px_num + (size_t)CH_ * BH_;
  float* px_norm = px_den + (size_t)CH_ * BH_;

  float* out  = (float*)d_out;
  float* xlast = out + (size_t)BT_ * H_;
  float* ndn   = xlast + (size_t)B_ * H_;

  const int cvt_blocks = (H_ * H_) / (256 * 8);
  cvt_bf16_kernel<<<cvt_blocks, 256, 0, stream>>>(Wk, Wk16);
  cvt_bf16_kernel<<<cvt_blocks, 256, 0, stream>>>(Wv, Wv16);
  cvt_bf16_kernel<<<cvt_blocks, 256, 0, stream>>>(Wr, Wr16);
  cvt_bf16_kernel<<<cvt_blocks, 256, 0, stream>>>(Wo, Wo16);

  ln_mix_kernel<<<BT_, 256, 0, stream>>>(h, lnw, lnb, mk, mv, mr, xk, xv, xr, xlast);

  dim3 gg(H_ / 128, BT_ / 128);
  gemm_nt<0><<<gg, 256, 0, stream>>>(xk, Wk16, kbuf, nullptr, nullptr);
  gemm_nt<0><<<gg, 256, 0, stream>>>(xv, Wv16, vbuf, nullptr, nullptr);
  gemm_nt<1><<<gg, 256, 0, stream>>>(xr, Wr16, nullptr, xv /* r reuses xv */, nullptr);

  dim3 wg(BH_ / 256, CH_);
  wkv_pass1<<<wg, 256, 0, stream>>>(kbuf, vbuf, td, cs_num, cs_den, cs_norm);
  wkv_scan<<<BH_ / 256, 256, 0, stream>>>(cs_num, cs_den, cs_norm, td,
                                          px_num, px_den, px_norm);
  wkv_pass2<<<wg, 256, 0, stream>>>(kbuf, vbuf, xv, td, cw,
                                    px_num, px_den, px_norm,
                                    xk /* a reuses xk */, ndn);

  gemm_nt<2><<<gg, 256, 0, stream>>>(xk, Wo16, out, nullptr, h);
}

// Round 4
// 434.627 us; speedup vs baseline: 2.0185x; 1.3458x over previous
//
#include <hip/hip_runtime.h>
#include <hip/hip_bf16.h>
#include <stdint.h>

// RWKV4 time-mix for B=4, T=2048, H=2048 on gfx950.
#define B_ 4
#define T_ 2048
#define H_ 2048
#define BT_ (B_ * T_)
#define BH_ (B_ * H_)
#define CH_ 32              // number of time chunks for the WKV scan
#define CL_ (T_ / CH_)      // chunk length = 64
#define NT_ (H_ / 32)       // 64 K-tiles of BK=32 for the GEMM

typedef __bf16 bf16x8 __attribute__((ext_vector_type(8)));
typedef float f32x4 __attribute__((ext_vector_type(4)));

// async global->LDS, 16B per lane. LDS dest is wave-uniform base + lane*16.
__device__ inline void async16(const void* g, void* l) {
  __builtin_amdgcn_global_load_lds(
      (__attribute__((address_space(1))) uint32_t*)(void*)(uintptr_t)g,
      (__attribute__((address_space(3))) uint32_t*)l,
      16, 0, 0);
}

// ---------------------------------------------------------------- f32 -> bf16
__global__ __launch_bounds__(256) void cvt_bf16_kernel(
    const float* __restrict__ src, __bf16* __restrict__ dst) {
  int i = (blockIdx.x * 256 + threadIdx.x) * 8;
  const float4* s4 = (const float4*)(src + i);
  float4 a = s4[0], b = s4[1];
  bf16x8 o;
  o[0] = (__bf16)a.x; o[1] = (__bf16)a.y; o[2] = (__bf16)a.z; o[3] = (__bf16)a.w;
  o[4] = (__bf16)b.x; o[5] = (__bf16)b.y; o[6] = (__bf16)b.z; o[7] = (__bf16)b.w;
  *(bf16x8*)(dst + i) = o;
}

// ------------------------------------------------- LayerNorm + token-shift mix
__global__ __launch_bounds__(256) void ln_mix_kernel(
    const float* __restrict__ h, const float* __restrict__ lnw,
    const float* __restrict__ lnb, const float* __restrict__ mk,
    const float* __restrict__ mv, const float* __restrict__ mr,
    __bf16* __restrict__ xk, __bf16* __restrict__ xv, __bf16* __restrict__ xr,
    float* __restrict__ xlast) {
  const int row = blockIdx.x;          // b*T + t
  const int t = row & (T_ - 1);
  const int tid = threadIdx.x;
  const bool hasprev = (t != 0);

  const float4* cr = (const float4*)(h + (size_t)row * H_);
  float4 c0 = cr[tid * 2 + 0], c1 = cr[tid * 2 + 1];
  float4 p0 = {0.f, 0.f, 0.f, 0.f}, p1 = {0.f, 0.f, 0.f, 0.f};
  if (hasprev) {
    const float4* pr = (const float4*)(h + (size_t)(row - 1) * H_);
    p0 = pr[tid * 2 + 0]; p1 = pr[tid * 2 + 1];
  }
  float4 red;
  red.x = c0.x + c0.y + c0.z + c0.w + c1.x + c1.y + c1.z + c1.w;
  red.y = c0.x * c0.x + c0.y * c0.y + c0.z * c0.z + c0.w * c0.w +
          c1.x * c1.x + c1.y * c1.y + c1.z * c1.z + c1.w * c1.w;
  red.z = p0.x + p0.y + p0.z + p0.w + p1.x + p1.y + p1.z + p1.w;
  red.w = p0.x * p0.x + p0.y * p0.y + p0.z * p0.z + p0.w * p0.w +
          p1.x * p1.x + p1.y * p1.y + p1.z * p1.z + p1.w * p1.w;
  #pragma unroll
  for (int off = 32; off; off >>= 1) {
    red.x += __shfl_down(red.x, off);
    red.y += __shfl_down(red.y, off);
    red.z += __shfl_down(red.z, off);
    red.w += __shfl_down(red.w, off);
  }
  __shared__ float4 rbuf[4];
  const int lane = tid & 63, wid = tid >> 6;
  if (lane == 0) rbuf[wid] = red;
  __syncthreads();
  float4 tot;
  tot.x = rbuf[0].x + rbuf[1].x + rbuf[2].x + rbuf[3].x;
  tot.y = rbuf[0].y + rbuf[1].y + rbuf[2].y + rbuf[3].y;
  tot.z = rbuf[0].z + rbuf[1].z + rbuf[2].z + rbuf[3].z;
  tot.w = rbuf[0].w + rbuf[1].w + rbuf[2].w + rbuf[3].w;

  const float inv = 1.0f / (float)H_;
  float mu = tot.x * inv;
  float rstd = rsqrtf(fmaxf(tot.y * inv - mu * mu, 0.f) + 1e-5f);
  float mup = tot.z * inv;
  float rstdp = rsqrtf(fmaxf(tot.w * inv - mup * mup, 0.f) + 1e-5f);

  float xc[8] = {c0.x, c0.y, c0.z, c0.w, c1.x, c1.y, c1.z, c1.w};
  float xp[8] = {p0.x, p0.y, p0.z, p0.w, p1.x, p1.y, p1.z, p1.w};
  const float4* W4 = (const float4*)lnw;
  const float4* Bv4 = (const float4*)lnb;
  const float4* MK4 = (const float4*)mk;
  const float4* MV4 = (const float4*)mv;
  const float4* MR4 = (const float4*)mr;
  float4 w0 = W4[tid * 2], w1 = W4[tid * 2 + 1];
  float4 b0 = Bv4[tid * 2], b1 = Bv4[tid * 2 + 1];
  float4 k0 = MK4[tid * 2], k1 = MK4[tid * 2 + 1];
  float4 v0 = MV4[tid * 2], v1 = MV4[tid * 2 + 1];
  float4 r0 = MR4[tid * 2], r1 = MR4[tid * 2 + 1];
  float wa[8] = {w0.x, w0.y, w0.z, w0.w, w1.x, w1.y, w1.z, w1.w};
  float ba[8] = {b0.x, b0.y, b0.z, b0.w, b1.x, b1.y, b1.z, b1.w};
  float ka[8] = {k0.x, k0.y, k0.z, k0.w, k1.x, k1.y, k1.z, k1.w};
  float va[8] = {v0.x, v0.y, v0.z, v0.w, v1.x, v1.y, v1.z, v1.w};
  float ra[8] = {r0.x, r0.y, r0.z, r0.w, r1.x, r1.y, r1.z, r1.w};

  bf16x8 ok_, ov_, or_;
  float xls[8];
  #pragma unroll
  for (int e = 0; e < 8; e++) {
    float x = (xc[e] - mu) * rstd * wa[e] + ba[e];
    float sx = hasprev ? (xp[e] - mup) * rstdp * wa[e] + ba[e] : 0.f;
    ok_[e] = (__bf16)(sx + ka[e] * (x - sx));
    ov_[e] = (__bf16)(sx + va[e] * (x - sx));
    or_[e] = (__bf16)(sx + ra[e] * (x - sx));
    xls[e] = x;
  }
  size_t obase = (size_t)row * H_ + tid * 8;
  *(bf16x8*)(xk + obase) = ok_;
  *(bf16x8*)(xv + obase) = ov_;
  *(bf16x8*)(xr + obase) = or_;
  if (t == T_ - 1) {
    float* dst = xlast + (size_t)(row >> 11) * H_ + tid * 8;
    #pragma unroll
    for (int e = 0; e < 8; e++) dst[e] = xls[e];
  }
}

// ------------------------------------------- bf16 NT GEMM, 256^2 pipelined
// C[m][o] = sum_h A[m][h] * W[o][h].  256x256 tile, BK=32, 8 waves (2Mx4N),
// 4-slot LDS ring (128 KiB), counted vmcnt(4) (2 tiles prefetch in flight),
// raw s_barrier (no vmcnt(0) drain), setprio around MFMA clusters.
// MODE 0: store f32. MODE 1: sigmoid -> bf16. MODE 2: residual add -> f32.

// Stage one pair of rounds for tile kt into slot: pair 0 = A-tile (rows 0-255),
// pair 1 = B-tile. Each call issues 2 async16 per thread (16 KiB per pair
// across 512 threads: round r covers 8 KiB = 128 rows of 64 B).
__device__ inline void stage_pair(const char* Ab, const char* Bb, char* slotbase,
                                  int kt, int pair, int wv, int lane) {
  const char* Mb = pair ? Bb : Ab;
  #pragma unroll
  for (int hlf = 0; hlf < 2; hlf++) {
    int r = pair * 2 + hlf;
    char* dst = slotbase + r * 8192 + wv * 1024;     // wave-uniform
    int row = hlf * 128 + wv * 16 + (lane >> 2);     // tile row 0..255
    const char* src = Mb + (size_t)row * (H_ * 2) + kt * 64 + (lane & 3) * 16;
    async16(src, dst);
  }
}

template <int MODE>
__global__ __launch_bounds__(512, 2) void gemm_nt2(
    const __bf16* __restrict__ A, const __bf16* __restrict__ Bw,
    float* __restrict__ outf, __bf16* __restrict__ outb,
    const float* __restrict__ resid) {
  // 4 slots x (A 16 KiB + B 16 KiB) = 128 KiB
  __shared__ __align__(16) char ring[4][32768];

  // bijective XCD swizzle: 256 blocks, 8 XCDs, chunks of 32 (4 bm-rows x 8 bn)
  const int wgid = blockIdx.x;
  const int lin = (wgid & 7) * 32 + (wgid >> 3);
  const int bm = lin >> 3;          // 0..31  (M/256)
  const int bn = lin & 7;           // 0..7   (N/256)

  const int tid = threadIdx.x;
  const int lane = tid & 63, wv = tid >> 6;
  const int wm = wv >> 2;           // 0..1
  const int wn = wv & 3;            // 0..3
  const int rr = lane & 15, q = lane >> 4;

  f32x4 acc[8][4];
  #pragma unroll
  for (int m = 0; m < 8; m++)
    #pragma unroll
    for (int n = 0; n < 4; n++) acc[m][n] = (f32x4){0.f, 0.f, 0.f, 0.f};

  const char* Ab = (const char*)A + (size_t)bm * 256 * (H_ * 2);
  const char* Bb = (const char*)Bw + (size_t)bn * 256 * (H_ * 2);

  // prologue: stage tiles 0 and 1; wait tile 0 (leave tile 1 in flight)
  stage_pair(Ab, Bb, ring[0], 0, 0, wv, lane);
  stage_pair(Ab, Bb, ring[0], 0, 1, wv, lane);
  stage_pair(Ab, Bb, ring[1], 1, 0, wv, lane);
  stage_pair(Ab, Bb, ring[1], 1, 1, wv, lane);
  asm volatile("s_waitcnt vmcnt(4)" ::: "memory");
  __builtin_amdgcn_s_barrier();

  for (int kt = 0; kt < NT_; kt++) {
    const __bf16* Alds = (const __bf16*)(ring[kt & 3]);
    const __bf16* Blds = (const __bf16*)(ring[kt & 3] + 16384);
    char* nslot = ring[(kt + 2) & 3];
    const bool pf = (kt + 2 < NT_);

    bf16x8 af[4], bfr[4];
    // ---------------- phase 0: quadrant mh=0 ----------------
    #pragma unroll
    for (int mi = 0; mi < 4; mi++)
      af[mi] = *(const bf16x8*)(Alds + (size_t)(wm * 128 + mi * 16 + rr) * 32 + q * 8);
    #pragma unroll
    for (int ni = 0; ni < 4; ni++)
      bfr[ni] = *(const bf16x8*)(Blds + (size_t)(wn * 64 + ni * 16 + rr) * 32 + q * 8);
    if (pf) stage_pair(Ab, Bb, nslot, kt + 2, 0, wv, lane);
    __builtin_amdgcn_sched_barrier(0);
    __builtin_amdgcn_s_barrier();
    __builtin_amdgcn_sched_barrier(0);
    __builtin_amdgcn_s_setprio(1);
    #pragma unroll
    for (int mi = 0; mi < 4; mi++)
      #pragma unroll
      for (int ni = 0; ni < 4; ni++)
        acc[mi][ni] = __builtin_amdgcn_mfma_f32_16x16x32_bf16(af[mi], bfr[ni], acc[mi][ni], 0, 0, 0);
    __builtin_amdgcn_s_setprio(0);
    __builtin_amdgcn_sched_barrier(0);
    __builtin_amdgcn_s_barrier();
    __builtin_amdgcn_sched_barrier(0);

    // ---------------- phase 1: quadrant mh=1 ----------------
    #pragma unroll
    for (int mi = 0; mi < 4; mi++)
      af[mi] = *(const bf16x8*)(Alds + (size_t)(wm * 128 + 64 + mi * 16 + rr) * 32 + q * 8);
    if (pf) stage_pair(Ab, Bb, nslot, kt + 2, 1, wv, lane);
    // end-of-tile wait: tile kt+1's 4 loads must be done; keep kt+2's in flight
    if (kt < NT_ - 2) {
      asm volatile("s_waitcnt vmcnt(4)" ::: "memory");
    } else {
      asm volatile("s_waitcnt vmcnt(0)" ::: "memory");
    }
    __builtin_amdgcn_sched_barrier(0);
    __builtin_amdgcn_s_barrier();
    __builtin_amdgcn_sched_barrier(0);
    __builtin_amdgcn_s_setprio(1);
    #pragma unroll
    for (int mi = 0; mi < 4; mi++)
      #pragma unroll
      for (int ni = 0; ni < 4; ni++)
        acc[4 + mi][ni] = __builtin_amdgcn_mfma_f32_16x16x32_bf16(af[mi], bfr[ni], acc[4 + mi][ni], 0, 0, 0);
    __builtin_amdgcn_s_setprio(0);
    __builtin_amdgcn_sched_barrier(0);
    __builtin_amdgcn_s_barrier();
    __builtin_amdgcn_sched_barrier(0);
  }

  // epilogue
  const int r0 = bm * 256 + wm * 128 + q * 4;
  const int c0 = bn * 256 + wn * 64 + rr;
  #pragma unroll
  for (int m = 0; m < 8; m++) {
    #pragma unroll
    for (int n = 0; n < 4; n++) {
      int col = c0 + n * 16;
      #pragma unroll
      for (int rg = 0; rg < 4; rg++) {
        int rowg = r0 + m * 16 + rg;
        size_t idx = (size_t)rowg * H_ + col;
        float vv = acc[m][n][rg];
        if (MODE == 0) {
          outf[idx] = vv;
        } else if (MODE == 1) {
          outb[idx] = (__bf16)(1.f / (1.f + __expf(-vv)));
        } else {
          outf[idx] = resid[idx] + vv;
        }
      }
    }
  }
}

// ------------------------------------------------- WKV chunked scan (3 passes)
__global__ __launch_bounds__(256) void wkv_pass1(
    const float* __restrict__ k, const float* __restrict__ v,
    const float* __restrict__ td,
    float* __restrict__ cs_num, float* __restrict__ cs_den,
    float* __restrict__ cs_norm) {
  const int id = blockIdx.x * 256 + threadIdx.x;  // 0..B*H-1
  const int c = blockIdx.y;                       // chunk
  const int b = id >> 11;
  const int hh = id & (H_ - 1);
  const float decay = -__expf(td[hh]);
  float num = 0.f, den = 0.f, norm = -INFINITY;

  const int UN = 16;
  for (int t0 = c * CL_; t0 < (c + 1) * CL_; t0 += UN) {
    float kk[UN], vv[UN];
    size_t base = ((size_t)b * T_ + t0) * H_ + hh;
    #pragma unroll
    for (int i = 0; i < UN; i++) {
      kk[i] = k[base + (size_t)i * H_];
      vv[i] = v[base + (size_t)i * H_];
    }
    #pragma unroll
    for (int i = 0; i < UN; i++) {
      float dpn = decay + norm;
      float nn = fmaxf(dpn, kk[i]);
      float ed = __expf(dpn - nn), ek = __expf(kk[i] - nn);
      num = ed * num + ek * vv[i];
      den = ed * den + ek;
      norm = nn;
    }
  }
  cs_num[c * BH_ + id] = num;
  cs_den[c * BH_ + id] = den;
  cs_norm[c * BH_ + id] = norm;
}

__global__ __launch_bounds__(256) void wkv_scan(
    const float* __restrict__ cs_num, const float* __restrict__ cs_den,
    const float* __restrict__ cs_norm, const float* __restrict__ td,
    float* __restrict__ px_num, float* __restrict__ px_den,
    float* __restrict__ px_norm) {
  const int id = blockIdx.x * 256 + threadIdx.x;  // 0..B*H-1
  const int hh = id & (H_ - 1);
  const float Lw = -__expf(td[hh]) * (float)CL_;  // CL_ * decay
  float num = 0.f, den = 0.f, norm = -INFINITY;
  for (int c = 0; c < CH_; c++) {
    px_num[c * BH_ + id] = num;
    px_den[c * BH_ + id] = den;
    px_norm[c * BH_ + id] = norm;
    float n_c = cs_num[c * BH_ + id];
    float d_c = cs_den[c * BH_ + id];
    float m_c = cs_norm[c * BH_ + id];
    float sn = norm + Lw;                 // shifted incoming norm
    float on = fmaxf(sn, m_c);            // m_c is always finite
    float ea = __expf(sn - on), eb = __expf(m_c - on);
    num = ea * num + eb * n_c;
    den = ea * den + eb * d_c;
    norm = on;
  }
}

__global__ __launch_bounds__(256) void wkv_pass2(
    const float* __restrict__ k, const float* __restrict__ v,
    const __bf16* __restrict__ r, const float* __restrict__ td,
    const float* __restrict__ cw,
    const float* __restrict__ px_num, const float* __restrict__ px_den,
    const float* __restrict__ px_norm,
    __bf16* __restrict__ a, float* __restrict__ ndn) {
  const int id = blockIdx.x * 256 + threadIdx.x;  // 0..B*H-1
  const int c = blockIdx.y;
  const int b = id >> 11;
  const int hh = id & (H_ - 1);
  const float decay = -__expf(td[hh]);
  const float cwv = cw[hh];
  float num = px_num[c * BH_ + id];
  float den = px_den[c * BH_ + id];
  float norm = px_norm[c * BH_ + id];

  const int UN = 16;
  for (int t0 = c * CL_; t0 < (c + 1) * CL_; t0 += UN) {
    float kk[UN], vv[UN], rrv[UN];
    size_t base = ((size_t)b * T_ + t0) * H_ + hh;
    #pragma unroll
    for (int i = 0; i < UN; i++) {
      kk[i] = k[base + (size_t)i * H_];
      vv[i] = v[base + (size_t)i * H_];
      rrv[i] = (float)r[base + (size_t)i * H_];
    }
    #pragma unroll
    for (int i = 0; i < UN; i++) {
      float kt = kk[i], vt = vv[i];
      float ct = cwv + kt;
      float cn = fmaxf(ct, norm);
      float ep = __expf(norm - cn), ec = __expf(ct - cn);
      float o = (ep * num + ec * vt) / (ep * den + ec);
      a[base + (size_t)i * H_] = (__bf16)(rrv[i] * o);
      float dpn = decay + norm;
      float nn = fmaxf(dpn, kt);
      float ed = __expf(dpn - nn), ek = __expf(kt - nn);
      num = ed * num + ek * vt;
      den = ed * den + ek;
      norm = nn;
    }
  }
  if (c == CH_ - 1) {
    ndn[id] = num;
    ndn[BH_ + id] = den;
    ndn[2 * BH_ + id] = norm;
  }
}

// ----------------------------------------------------------------------- host
extern "C" void kernel_launch(void* const* d_in, const int* in_sizes, int n_in,
                              void* d_out, int out_size, void* d_ws, size_t ws_size,
                              hipStream_t stream) {
  const float* h   = (const float*)d_in[0];
  const float* lnw = (const float*)d_in[1];
  const float* lnb = (const float*)d_in[2];
  const float* Wk  = (const float*)d_in[3];
  const float* Wv  = (const float*)d_in[4];
  const float* Wr  = (const float*)d_in[5];
  const float* Wo  = (const float*)d_in[6];
  const float* mk  = (const float*)d_in[7];
  const float* mv  = (const float*)d_in[8];
  const float* mr  = (const float*)d_in[9];
  const float* td  = (const float*)d_in[10];
  const float* cw  = (const float*)d_in[11];

  char* ws = (char*)d_ws;
  const size_t MB = 1048576;
  // 256 MB workspace layout:
  //   [0,32)    xk   (bf16, later reused as 'a' = r*wkv)
  //   [32,64)   xv   (bf16, later reused as 'r')
  //   [64,96)   xr   (bf16; dead after r-GEMM -> scan state lives here)
  //   [96,160)  kbuf (f32)
  //   [160,224) vbuf (f32)
  //   [224,256) Wk16/Wv16/Wr16/Wo16 (bf16, 8 MB each)
  __bf16* xk   = (__bf16*)(ws);
  __bf16* xv   = (__bf16*)(ws + 32 * MB);
  __bf16* xr   = (__bf16*)(ws + 64 * MB);
  float*  kbuf = (float*)(ws + 96 * MB);
  float*  vbuf = (float*)(ws + 160 * MB);
  __bf16* Wk16 = (__bf16*)(ws + 224 * MB);
  __bf16* Wv16 = Wk16 + (size_t)H_ * H_;
  __bf16* Wr16 = Wv16 + (size_t)H_ * H_;
  __bf16* Wo16 = Wr16 + (size_t)H_ * H_;
  float* cs_num  = (float*)(ws + 64 * MB);
  float* cs_den  = cs_num + (size_t)CH_ * BH_;
  float* cs_norm = cs_den + (size_t)CH_ * BH_;
  float* px_num  = cs_norm + (size_t)CH_ * BH_;
  float* px_den  = px_num + (size_t)CH_ * BH_;
  float* px_norm = px_den + (size_t)CH_ * BH_;

  float* out  = (float*)d_out;
  float* xlast = out + (size_t)BT_ * H_;
  float* ndn   = xlast + (size_t)B_ * H_;

  const int cvt_blocks = (H_ * H_) / (256 * 8);
  cvt_bf16_kernel<<<cvt_blocks, 256, 0, stream>>>(Wk, Wk16);
  cvt_bf16_kernel<<<cvt_blocks, 256, 0, stream>>>(Wv, Wv16);
  cvt_bf16_kernel<<<cvt_blocks, 256, 0, stream>>>(Wr, Wr16);
  cvt_bf16_kernel<<<cvt_blocks, 256, 0, stream>>>(Wo, Wo16);

  ln_mix_kernel<<<BT_, 256, 0, stream>>>(h, lnw, lnb, mk, mv, mr, xk, xv, xr, xlast);

  const int gemm_blocks = (BT_ / 256) * (H_ / 256);  // 32 * 8 = 256
  gemm_nt2<0><<<gemm_blocks, 512, 0, stream>>>(xk, Wk16, kbuf, nullptr, nullptr);
  gemm_nt2<0><<<gemm_blocks, 512, 0, stream>>>(xv, Wv16, vbuf, nullptr, nullptr);
  gemm_nt2<1><<<gemm_blocks, 512, 0, stream>>>(xr, Wr16, nullptr, xv /* r reuses xv */, nullptr);

  dim3 wg(BH_ / 256, CH_);
  wkv_pass1<<<wg, 256, 0, stream>>>(kbuf, vbuf, td, cs_num, cs_den, cs_norm);
  wkv_scan<<<BH_ / 256, 256, 0, stream>>>(cs_num, cs_den, cs_norm, td,
                                          px_num, px_den, px_norm);
  wkv_pass2<<<wg, 256, 0, stream>>>(kbuf, vbuf, xv, td, cw,
                                    px_num, px_den, px_norm,
                                    xk /* a reuses xk */, ndn);

  gemm_nt2<2><<<gemm_blocks, 512, 0, stream>>>(xk, Wo16, out, nullptr, h);
}

// Round 5
// 429.577 us; speedup vs baseline: 2.0423x; 1.0118x over previous
//
#include <hip/hip_runtime.h>
#include <hip/hip_bf16.h>
#include <stdint.h>

// RWKV4 time-mix for B=4, T=2048, H=2048 on gfx950.
#define B_ 4
#define T_ 2048
#define H_ 2048
#define BT_ (B_ * T_)
#define BH_ (B_ * H_)
#define CH_ 32              // number of time chunks for the WKV scan
#define CL_ (T_ / CH_)      // chunk length = 64
#define NKT_ (H_ / 64)      // 32 K-tiles of BK=64 for the GEMM

typedef __bf16 bf16x8 __attribute__((ext_vector_type(8)));
typedef float f32x4 __attribute__((ext_vector_type(4)));

// async global->LDS, 16B per lane. LDS dest is wave-uniform base + lane*16.
__device__ inline void async16(const void* g, void* l) {
  __builtin_amdgcn_global_load_lds(
      (__attribute__((address_space(1))) uint32_t*)(void*)(uintptr_t)g,
      (__attribute__((address_space(3))) uint32_t*)l,
      16, 0, 0);
}

// ---------------------------------------------------------------- f32 -> bf16
__global__ __launch_bounds__(256) void cvt_bf16_kernel(
    const float* __restrict__ src, __bf16* __restrict__ dst) {
  int i = (blockIdx.x * 256 + threadIdx.x) * 8;
  const float4* s4 = (const float4*)(src + i);
  float4 a = s4[0], b = s4[1];
  bf16x8 o;
  o[0] = (__bf16)a.x; o[1] = (__bf16)a.y; o[2] = (__bf16)a.z; o[3] = (__bf16)a.w;
  o[4] = (__bf16)b.x; o[5] = (__bf16)b.y; o[6] = (__bf16)b.z; o[7] = (__bf16)b.w;
  *(bf16x8*)(dst + i) = o;
}

// ------------------------------------------------- LayerNorm + token-shift mix
__global__ __launch_bounds__(256) void ln_mix_kernel(
    const float* __restrict__ h, const float* __restrict__ lnw,
    const float* __restrict__ lnb, const float* __restrict__ mk,
    const float* __restrict__ mv, const float* __restrict__ mr,
    __bf16* __restrict__ xk, __bf16* __restrict__ xv, __bf16* __restrict__ xr,
    float* __restrict__ xlast) {
  const int row = blockIdx.x;          // b*T + t
  const int t = row & (T_ - 1);
  const int tid = threadIdx.x;
  const bool hasprev = (t != 0);

  const float4* cr = (const float4*)(h + (size_t)row * H_);
  float4 c0 = cr[tid * 2 + 0], c1 = cr[tid * 2 + 1];
  float4 p0 = {0.f, 0.f, 0.f, 0.f}, p1 = {0.f, 0.f, 0.f, 0.f};
  if (hasprev) {
    const float4* pr = (const float4*)(h + (size_t)(row - 1) * H_);
    p0 = pr[tid * 2 + 0]; p1 = pr[tid * 2 + 1];
  }
  float4 red;
  red.x = c0.x + c0.y + c0.z + c0.w + c1.x + c1.y + c1.z + c1.w;
  red.y = c0.x * c0.x + c0.y * c0.y + c0.z * c0.z + c0.w * c0.w +
          c1.x * c1.x + c1.y * c1.y + c1.z * c1.z + c1.w * c1.w;
  red.z = p0.x + p0.y + p0.z + p0.w + p1.x + p1.y + p1.z + p1.w;
  red.w = p0.x * p0.x + p0.y * p0.y + p0.z * p0.z + p0.w * p0.w +
          p1.x * p1.x + p1.y * p1.y + p1.z * p1.z + p1.w * p1.w;
  #pragma unroll
  for (int off = 32; off; off >>= 1) {
    red.x += __shfl_down(red.x, off);
    red.y += __shfl_down(red.y, off);
    red.z += __shfl_down(red.z, off);
    red.w += __shfl_down(red.w, off);
  }
  __shared__ float4 rbuf[4];
  const int lane = tid & 63, wid = tid >> 6;
  if (lane == 0) rbuf[wid] = red;
  __syncthreads();
  float4 tot;
  tot.x = rbuf[0].x + rbuf[1].x + rbuf[2].x + rbuf[3].x;
  tot.y = rbuf[0].y + rbuf[1].y + rbuf[2].y + rbuf[3].y;
  tot.z = rbuf[0].z + rbuf[1].z + rbuf[2].z + rbuf[3].z;
  tot.w = rbuf[0].w + rbuf[1].w + rbuf[2].w + rbuf[3].w;

  const float inv = 1.0f / (float)H_;
  float mu = tot.x * inv;
  float rstd = rsqrtf(fmaxf(tot.y * inv - mu * mu, 0.f) + 1e-5f);
  float mup = tot.z * inv;
  float rstdp = rsqrtf(fmaxf(tot.w * inv - mup * mup, 0.f) + 1e-5f);

  float xc[8] = {c0.x, c0.y, c0.z, c0.w, c1.x, c1.y, c1.z, c1.w};
  float xp[8] = {p0.x, p0.y, p0.z, p0.w, p1.x, p1.y, p1.z, p1.w};
  const float4* W4 = (const float4*)lnw;
  const float4* Bv4 = (const float4*)lnb;
  const float4* MK4 = (const float4*)mk;
  const float4* MV4 = (const float4*)mv;
  const float4* MR4 = (const float4*)mr;
  float4 w0 = W4[tid * 2], w1 = W4[tid * 2 + 1];
  float4 b0 = Bv4[tid * 2], b1 = Bv4[tid * 2 + 1];
  float4 k0 = MK4[tid * 2], k1 = MK4[tid * 2 + 1];
  float4 v0 = MV4[tid * 2], v1 = MV4[tid * 2 + 1];
  float4 r0 = MR4[tid * 2], r1 = MR4[tid * 2 + 1];
  float wa[8] = {w0.x, w0.y, w0.z, w0.w, w1.x, w1.y, w1.z, w1.w};
  float ba[8] = {b0.x, b0.y, b0.z, b0.w, b1.x, b1.y, b1.z, b1.w};
  float ka[8] = {k0.x, k0.y, k0.z, k0.w, k1.x, k1.y, k1.z, k1.w};
  float va[8] = {v0.x, v0.y, v0.z, v0.w, v1.x, v1.y, v1.z, v1.w};
  float ra[8] = {r0.x, r0.y, r0.z, r0.w, r1.x, r1.y, r1.z, r1.w};

  bf16x8 ok_, ov_, or_;
  float xls[8];
  #pragma unroll
  for (int e = 0; e < 8; e++) {
    float x = (xc[e] - mu) * rstd * wa[e] + ba[e];
    float sx = hasprev ? (xp[e] - mup) * rstdp * wa[e] + ba[e] : 0.f;
    ok_[e] = (__bf16)(sx + ka[e] * (x - sx));
    ov_[e] = (__bf16)(sx + va[e] * (x - sx));
    or_[e] = (__bf16)(sx + ra[e] * (x - sx));
    xls[e] = x;
  }
  size_t obase = (size_t)row * H_ + tid * 8;
  *(bf16x8*)(xk + obase) = ok_;
  *(bf16x8*)(xv + obase) = ov_;
  *(bf16x8*)(xr + obase) = or_;
  if (t == T_ - 1) {
    float* dst = xlast + (size_t)(row >> 11) * H_ + tid * 8;
    #pragma unroll
    for (int e = 0; e < 8; e++) dst[e] = xls[e];
  }
}

// ----------------------- bf16 NT GEMM, 256^2 tile, BK=64, swizzled LDS (m201)
// C[m][o] = sum_h A[m][h] * W[o][h].  8 waves (2Mx4N), per-wave 128x64 output.
// 2-buffer LDS (2 x (A 32K + B 32K) = 128 KiB).  4 phases per K-tile, each
// phase = one 32x64 C-quadrant x K=64 = 16 MFMA.  LDS rows are 128 B (BK=64
// bf16); XOR-swizzle byte ^= (row&7)<<4 applied on BOTH sides: inverse on the
// per-lane global source of global_load_lds (LDS dest stays linear), forward
// on ds_read addresses -> conflict-free b128 reads (T2).
// Staging: all 4 half-tiles of tile kt+1 issued at phase 0 of tile kt into
// the buffer last read at tile kt-1 (safe: phase-3 post-barrier of kt-1);
// single vmcnt(0) at phase 3 covers ~3 phases of latency (T3/T4).
// MODE 0: store f32. MODE 1: sigmoid -> bf16. MODE 2: residual add -> f32.
template <int MODE>
__global__ __launch_bounds__(512, 1) void gemm_nt3(
    const __bf16* __restrict__ A, const __bf16* __restrict__ Bw,
    float* __restrict__ outf, __bf16* __restrict__ outb,
    const float* __restrict__ resid) {
  __shared__ __align__(16) char ring[2][65536];   // [buf][A 32K | B 32K]

  // bijective XCD swizzle: 256 blocks, 8 XCDs, chunks of 32 (4 bm-rows x 8 bn)
  const int wgid = blockIdx.x;
  const int lin = (wgid & 7) * 32 + (wgid >> 3);
  const int bm = lin >> 3;          // 0..31  (M/256)
  const int bn = lin & 7;           // 0..7   (N/256)

  const int tid = threadIdx.x;
  const int lane = tid & 63, wv = tid >> 6;
  const int wm = wv >> 2;           // 0..1
  const int wn = wv & 3;            // 0..3
  const int rr = lane & 15, q = lane >> 4;

  f32x4 acc[8][4];
  #pragma unroll
  for (int m = 0; m < 8; m++)
    #pragma unroll
    for (int n = 0; n < 4; n++) acc[m][n] = (f32x4){0.f, 0.f, 0.f, 0.f};

  const char* Ag = (const char*)A + (size_t)(bm * 256) * (H_ * 2);
  const char* Bg = (const char*)Bw + (size_t)(bn * 256) * (H_ * 2);

  // stage addressing: round = 64 rows x 128 B; lane l covers row wv*8+(l>>3),
  // 16-B col (l&7), fetching global col (l&7)^(l>>3)  (inverse swizzle).
  const int srow = wv * 8 + (lane >> 3);
  const int scol = ((lane & 7) ^ (lane >> 3)) << 4;

  // ds_read swizzle: row&7 == rr&7 for all fragment reads.
  const int rsw = rr & 7;

#define STAGE_TILE(kt_, buf_)                                                   \
  {                                                                             \
    char* base_ = ring[buf_];                                                   \
    _Pragma("unroll")                                                           \
    for (int mh_ = 0; mh_ < 2; mh_++) {                                         \
      const char* Mg_ = mh_ ? Bg : Ag;                                          \
      _Pragma("unroll")                                                         \
      for (int hh_ = 0; hh_ < 2; hh_++) {                                       \
        _Pragma("unroll")                                                       \
        for (int rd_ = 0; rd_ < 2; rd_++) {                                     \
          char* dst_ = base_ + mh_ * 32768 + hh_ * 16384 + rd_ * 8192 + wv * 1024; \
          const char* src_ = Mg_ + (size_t)(hh_ * 128 + rd_ * 64 + srow) * (H_ * 2) \
                             + (kt_) * 128 + scol;                              \
          async16(src_, dst_);                                                  \
        }                                                                       \
      }                                                                         \
    }                                                                           \
  }

  // prologue: stage tile 0, drain, barrier.
  STAGE_TILE(0, 0);
  asm volatile("s_waitcnt vmcnt(0)" ::: "memory");
  __builtin_amdgcn_s_barrier();

  bf16x8 bfr[4][2];   // B-fragments, held across the 4 phases of a tile

  for (int kt = 0; kt < NKT_; kt++) {
    const int cur = kt & 1, nxt = cur ^ 1;
    const char* Alds = ring[cur];
    const char* Blds = ring[cur] + 32768;

    #pragma unroll
    for (int p = 0; p < 4; p++) {
      // ---- ds_read this phase's fragments (pre-barrier) ----
      if (p == 0) {
        #pragma unroll
        for (int ni = 0; ni < 4; ni++)
          #pragma unroll
          for (int ks = 0; ks < 2; ks++) {
            int row_t = wn * 64 + ni * 16 + rr;
            bfr[ni][ks] = *(const bf16x8*)(Blds + row_t * 128 +
                                           (((ks * 4 + q) ^ rsw) << 4));
          }
      }
      bf16x8 af[2][2];
      #pragma unroll
      for (int mi = 0; mi < 2; mi++)
        #pragma unroll
        for (int ks = 0; ks < 2; ks++) {
          int row_t = wm * 128 + p * 32 + mi * 16 + rr;
          af[mi][ks] = *(const bf16x8*)(Alds + row_t * 128 +
                                        (((ks * 4 + q) ^ rsw) << 4));
        }
      // ---- stage next tile (phase 0 only); drain at phase 3 ----
      if (p == 0 && kt + 1 < NKT_) STAGE_TILE(kt + 1, nxt);
      if (p == 3) asm volatile("s_waitcnt vmcnt(0)" ::: "memory");
      __builtin_amdgcn_sched_barrier(0);
      __builtin_amdgcn_s_barrier();
      __builtin_amdgcn_sched_barrier(0);
      asm volatile("s_waitcnt lgkmcnt(0)" ::: "memory");
      __builtin_amdgcn_sched_barrier(0);
      __builtin_amdgcn_s_setprio(1);
      #pragma unroll
      for (int ks = 0; ks < 2; ks++)
        #pragma unroll
        for (int mi = 0; mi < 2; mi++)
          #pragma unroll
          for (int ni = 0; ni < 4; ni++)
            acc[p * 2 + mi][ni] = __builtin_amdgcn_mfma_f32_16x16x32_bf16(
                af[mi][ks], bfr[ni][ks], acc[p * 2 + mi][ni], 0, 0, 0);
      __builtin_amdgcn_s_setprio(0);
      __builtin_amdgcn_sched_barrier(0);
      __builtin_amdgcn_s_barrier();
      __builtin_amdgcn_sched_barrier(0);
    }
  }
#undef STAGE_TILE

  // epilogue: acc[m][n] row = bm*256 + wm*128 + m*16 + q*4 + rg, col = bn*256
  // + wn*64 + n*16 + rr.
  const int r0 = bm * 256 + wm * 128 + q * 4;
  const int c0 = bn * 256 + wn * 64 + rr;
  #pragma unroll
  for (int m = 0; m < 8; m++) {
    #pragma unroll
    for (int n = 0; n < 4; n++) {
      int col = c0 + n * 16;
      #pragma unroll
      for (int rg = 0; rg < 4; rg++) {
        int rowg = r0 + m * 16 + rg;
        size_t idx = (size_t)rowg * H_ + col;
        float vv = acc[m][n][rg];
        if (MODE == 0) {
          outf[idx] = vv;
        } else if (MODE == 1) {
          outb[idx] = (__bf16)(1.f / (1.f + __expf(-vv)));
        } else {
          outf[idx] = resid[idx] + vv;
        }
      }
    }
  }
}

// ------------------------------------------------- WKV chunked scan (3 passes)
__global__ __launch_bounds__(256) void wkv_pass1(
    const float* __restrict__ k, const float* __restrict__ v,
    const float* __restrict__ td,
    float* __restrict__ cs_num, float* __restrict__ cs_den,
    float* __restrict__ cs_norm) {
  const int id = blockIdx.x * 256 + threadIdx.x;  // 0..B*H-1
  const int c = blockIdx.y;                       // chunk
  const int b = id >> 11;
  const int hh = id & (H_ - 1);
  const float decay = -__expf(td[hh]);
  float num = 0.f, den = 0.f, norm = -INFINITY;

  const int UN = 16;
  for (int t0 = c * CL_; t0 < (c + 1) * CL_; t0 += UN) {
    float kk[UN], vv[UN];
    size_t base = ((size_t)b * T_ + t0) * H_ + hh;
    #pragma unroll
    for (int i = 0; i < UN; i++) {
      kk[i] = k[base + (size_t)i * H_];
      vv[i] = v[base + (size_t)i * H_];
    }
    #pragma unroll
    for (int i = 0; i < UN; i++) {
      float dpn = decay + norm;
      float nn = fmaxf(dpn, kk[i]);
      float ed = __expf(dpn - nn), ek = __expf(kk[i] - nn);
      num = ed * num + ek * vv[i];
      den = ed * den + ek;
      norm = nn;
    }
  }
  cs_num[c * BH_ + id] = num;
  cs_den[c * BH_ + id] = den;
  cs_norm[c * BH_ + id] = norm;
}

__global__ __launch_bounds__(256) void wkv_scan(
    const float* __restrict__ cs_num, const float* __restrict__ cs_den,
    const float* __restrict__ cs_norm, const float* __restrict__ td,
    float* __restrict__ px_num, float* __restrict__ px_den,
    float* __restrict__ px_norm) {
  const int id = blockIdx.x * 256 + threadIdx.x;  // 0..B*H-1
  const int hh = id & (H_ - 1);
  const float Lw = -__expf(td[hh]) * (float)CL_;  // CL_ * decay
  float num = 0.f, den = 0.f, norm = -INFINITY;
  for (int c = 0; c < CH_; c++) {
    px_num[c * BH_ + id] = num;
    px_den[c * BH_ + id] = den;
    px_norm[c * BH_ + id] = norm;
    float n_c = cs_num[c * BH_ + id];
    float d_c = cs_den[c * BH_ + id];
    float m_c = cs_norm[c * BH_ + id];
    float sn = norm + Lw;                 // shifted incoming norm
    float on = fmaxf(sn, m_c);            // m_c is always finite
    float ea = __expf(sn - on), eb = __expf(m_c - on);
    num = ea * num + eb * n_c;
    den = ea * den + eb * d_c;
    norm = on;
  }
}

__global__ __launch_bounds__(256) void wkv_pass2(
    const float* __restrict__ k, const float* __restrict__ v,
    const __bf16* __restrict__ r, const float* __restrict__ td,
    const float* __restrict__ cw,
    const float* __restrict__ px_num, const float* __restrict__ px_den,
    const float* __restrict__ px_norm,
    __bf16* __restrict__ a, float* __restrict__ ndn) {
  const int id = blockIdx.x * 256 + threadIdx.x;  // 0..B*H-1
  const int c = blockIdx.y;
  const int b = id >> 11;
  const int hh = id & (H_ - 1);
  const float decay = -__expf(td[hh]);
  const float cwv = cw[hh];
  float num = px_num[c * BH_ + id];
  float den = px_den[c * BH_ + id];
  float norm = px_norm[c * BH_ + id];

  const int UN = 16;
  for (int t0 = c * CL_; t0 < (c + 1) * CL_; t0 += UN) {
    float kk[UN], vv[UN], rrv[UN];
    size_t base = ((size_t)b * T_ + t0) * H_ + hh;
    #pragma unroll
    for (int i = 0; i < UN; i++) {
      kk[i] = k[base + (size_t)i * H_];
      vv[i] = v[base + (size_t)i * H_];
      rrv[i] = (float)r[base + (size_t)i * H_];
    }
    #pragma unroll
    for (int i = 0; i < UN; i++) {
      float kt = kk[i], vt = vv[i];
      float ct = cwv + kt;
      float cn = fmaxf(ct, norm);
      float ep = __expf(norm - cn), ec = __expf(ct - cn);
      float o = (ep * num + ec * vt) / (ep * den + ec);
      a[base + (size_t)i * H_] = (__bf16)(rrv[i] * o);
      float dpn = decay + norm;
      float nn = fmaxf(dpn, kt);
      float ed = __expf(dpn - nn), ek = __expf(kt - nn);
      num = ed * num + ek * vt;
      den = ed * den + ek;
      norm = nn;
    }
  }
  if (c == CH_ - 1) {
    ndn[id] = num;
    ndn[BH_ + id] = den;
    ndn[2 * BH_ + id] = norm;
  }
}

// ----------------------------------------------------------------------- host
extern "C" void kernel_launch(void* const* d_in, const int* in_sizes, int n_in,
                              void* d_out, int out_size, void* d_ws, size_t ws_size,
                              hipStream_t stream) {
  const float* h   = (const float*)d_in[0];
  const float* lnw = (const float*)d_in[1];
  const float* lnb = (const float*)d_in[2];
  const float* Wk  = (const float*)d_in[3];
  const float* Wv  = (const float*)d_in[4];
  const float* Wr  = (const float*)d_in[5];
  const float* Wo  = (const float*)d_in[6];
  const float* mk  = (const float*)d_in[7];
  const float* mv  = (const float*)d_in[8];
  const float* mr  = (const float*)d_in[9];
  const float* td  = (const float*)d_in[10];
  const float* cw  = (const float*)d_in[11];

  char* ws = (char*)d_ws;
  const size_t MB = 1048576;
  // 256 MB workspace layout:
  //   [0,32)    xk   (bf16, later reused as 'a' = r*wkv)
  //   [32,64)   xv   (bf16, later reused as 'r')
  //   [64,96)   xr   (bf16; dead after r-GEMM -> scan state lives here)
  //   [96,160)  kbuf (f32)
  //   [160,224) vbuf (f32)
  //   [224,256) Wk16/Wv16/Wr16/Wo16 (bf16, 8 MB each)
  __bf16* xk   = (__bf16*)(ws);
  __bf16* xv   = (__bf16*)(ws + 32 * MB);
  __bf16* xr   = (__bf16*)(ws + 64 * MB);
  float*  kbuf = (float*)(ws + 96 * MB);
  float*  vbuf = (float*)(ws + 160 * MB);
  __bf16* Wk16 = (__bf16*)(ws + 224 * MB);
  __bf16* Wv16 = Wk16 + (size_t)H_ * H_;
  __bf16* Wr16 = Wv16 + (size_t)H_ * H_;
  __bf16* Wo16 = Wr16 + (size_t)H_ * H_;
  float* cs_num  = (float*)(ws + 64 * MB);
  float* cs_den  = cs_num + (size_t)CH_ * BH_;
  float* cs_norm = cs_den + (size_t)CH_ * BH_;
  float* px_num  = cs_norm + (size_t)CH_ * BH_;
  float* px_den  = px_num + (size_t)CH_ * BH_;
  float* px_norm = px_den + (size_t)CH_ * BH_;

  float* out  = (float*)d_out;
  float* xlast = out + (size_t)BT_ * H_;
  float* ndn   = xlast + (size_t)B_ * H_;

  const int cvt_blocks = (H_ * H_) / (256 * 8);
  cvt_bf16_kernel<<<cvt_blocks, 256, 0, stream>>>(Wk, Wk16);
  cvt_bf16_kernel<<<cvt_blocks, 256, 0, stream>>>(Wv, Wv16);
  cvt_bf16_kernel<<<cvt_blocks, 256, 0, stream>>>(Wr, Wr16);
  cvt_bf16_kernel<<<cvt_blocks, 256, 0, stream>>>(Wo, Wo16);

  ln_mix_kernel<<<BT_, 256, 0, stream>>>(h, lnw, lnb, mk, mv, mr, xk, xv, xr, xlast);

  const int gemm_blocks = (BT_ / 256) * (H_ / 256);  // 32 * 8 = 256
  gemm_nt3<0><<<gemm_blocks, 512, 0, stream>>>(xk, Wk16, kbuf, nullptr, nullptr);
  gemm_nt3<0><<<gemm_blocks, 512, 0, stream>>>(xv, Wv16, vbuf, nullptr, nullptr);
  gemm_nt3<1><<<gemm_blocks, 512, 0, stream>>>(xr, Wr16, nullptr, xv /* r reuses xv */, nullptr);

  dim3 wg(BH_ / 256, CH_);
  wkv_pass1<<<wg, 256, 0, stream>>>(kbuf, vbuf, td, cs_num, cs_den, cs_norm);
  wkv_scan<<<BH_ / 256, 256, 0, stream>>>(cs_num, cs_den, cs_norm, td,
                                          px_num, px_den, px_norm);
  wkv_pass2<<<wg, 256, 0, stream>>>(kbuf, vbuf, xv, td, cw,
                                    px_num, px_den, px_norm,
                                    xk /* a reuses xk */, ndn);

  gemm_nt3<2><<<gemm_blocks, 512, 0, stream>>>(xk, Wo16, out, nullptr, h);
}

// Round 6
// 398.773 us; speedup vs baseline: 2.2000x; 1.0772x over previous
//
#include <hip/hip_runtime.h>
#include <hip/hip_bf16.h>
#include <stdint.h>

// RWKV4 time-mix for B=4, T=2048, H=2048 on gfx950.
#define B_ 4
#define T_ 2048
#define H_ 2048
#define BT_ (B_ * T_)
#define BH_ (B_ * H_)
#define CH_ 32              // number of time chunks for the WKV scan
#define CL_ (T_ / CH_)      // chunk length = 64
#define NKT_ (H_ / 64)      // 32 K-tiles of BK=64 for the GEMM

typedef __bf16 bf16x8 __attribute__((ext_vector_type(8)));
typedef float f32x4 __attribute__((ext_vector_type(4)));

// async global->LDS, 16B per lane. LDS dest is wave-uniform base + lane*16.
__device__ inline void async16(const void* g, void* l) {
  __builtin_amdgcn_global_load_lds(
      (__attribute__((address_space(1))) uint32_t*)(void*)(uintptr_t)g,
      (__attribute__((address_space(3))) uint32_t*)l,
      16, 0, 0);
}

// ---------------------------------------------------------------- f32 -> bf16
__global__ __launch_bounds__(256) void cvt_bf16_kernel(
    const float* __restrict__ src, __bf16* __restrict__ dst) {
  int i = (blockIdx.x * 256 + threadIdx.x) * 8;
  const float4* s4 = (const float4*)(src + i);
  float4 a = s4[0], b = s4[1];
  bf16x8 o;
  o[0] = (__bf16)a.x; o[1] = (__bf16)a.y; o[2] = (__bf16)a.z; o[3] = (__bf16)a.w;
  o[4] = (__bf16)b.x; o[5] = (__bf16)b.y; o[6] = (__bf16)b.z; o[7] = (__bf16)b.w;
  *(bf16x8*)(dst + i) = o;
}

// ------------------------------------------------- LayerNorm + token-shift mix
__global__ __launch_bounds__(256) void ln_mix_kernel(
    const float* __restrict__ h, const float* __restrict__ lnw,
    const float* __restrict__ lnb, const float* __restrict__ mk,
    const float* __restrict__ mv, const float* __restrict__ mr,
    __bf16* __restrict__ xk, __bf16* __restrict__ xv, __bf16* __restrict__ xr,
    float* __restrict__ xlast) {
  const int row = blockIdx.x;          // b*T + t
  const int t = row & (T_ - 1);
  const int tid = threadIdx.x;
  const bool hasprev = (t != 0);

  const float4* cr = (const float4*)(h + (size_t)row * H_);
  float4 c0 = cr[tid * 2 + 0], c1 = cr[tid * 2 + 1];
  float4 p0 = {0.f, 0.f, 0.f, 0.f}, p1 = {0.f, 0.f, 0.f, 0.f};
  if (hasprev) {
    const float4* pr = (const float4*)(h + (size_t)(row - 1) * H_);
    p0 = pr[tid * 2 + 0]; p1 = pr[tid * 2 + 1];
  }
  float4 red;
  red.x = c0.x + c0.y + c0.z + c0.w + c1.x + c1.y + c1.z + c1.w;
  red.y = c0.x * c0.x + c0.y * c0.y + c0.z * c0.z + c0.w * c0.w +
          c1.x * c1.x + c1.y * c1.y + c1.z * c1.z + c1.w * c1.w;
  red.z = p0.x + p0.y + p0.z + p0.w + p1.x + p1.y + p1.z + p1.w;
  red.w = p0.x * p0.x + p0.y * p0.y + p0.z * p0.z + p0.w * p0.w +
          p1.x * p1.x + p1.y * p1.y + p1.z * p1.z + p1.w * p1.w;
  #pragma unroll
  for (int off = 32; off; off >>= 1) {
    red.x += __shfl_down(red.x, off);
    red.y += __shfl_down(red.y, off);
    red.z += __shfl_down(red.z, off);
    red.w += __shfl_down(red.w, off);
  }
  __shared__ float4 rbuf[4];
  const int lane = tid & 63, wid = tid >> 6;
  if (lane == 0) rbuf[wid] = red;
  __syncthreads();
  float4 tot;
  tot.x = rbuf[0].x + rbuf[1].x + rbuf[2].x + rbuf[3].x;
  tot.y = rbuf[0].y + rbuf[1].y + rbuf[2].y + rbuf[3].y;
  tot.z = rbuf[0].z + rbuf[1].z + rbuf[2].z + rbuf[3].z;
  tot.w = rbuf[0].w + rbuf[1].w + rbuf[2].w + rbuf[3].w;

  const float inv = 1.0f / (float)H_;
  float mu = tot.x * inv;
  float rstd = rsqrtf(fmaxf(tot.y * inv - mu * mu, 0.f) + 1e-5f);
  float mup = tot.z * inv;
  float rstdp = rsqrtf(fmaxf(tot.w * inv - mup * mup, 0.f) + 1e-5f);

  float xc[8] = {c0.x, c0.y, c0.z, c0.w, c1.x, c1.y, c1.z, c1.w};
  float xp[8] = {p0.x, p0.y, p0.z, p0.w, p1.x, p1.y, p1.z, p1.w};
  const float4* W4 = (const float4*)lnw;
  const float4* Bv4 = (const float4*)lnb;
  const float4* MK4 = (const float4*)mk;
  const float4* MV4 = (const float4*)mv;
  const float4* MR4 = (const float4*)mr;
  float4 w0 = W4[tid * 2], w1 = W4[tid * 2 + 1];
  float4 b0 = Bv4[tid * 2], b1 = Bv4[tid * 2 + 1];
  float4 k0 = MK4[tid * 2], k1 = MK4[tid * 2 + 1];
  float4 v0 = MV4[tid * 2], v1 = MV4[tid * 2 + 1];
  float4 r0 = MR4[tid * 2], r1 = MR4[tid * 2 + 1];
  float wa[8] = {w0.x, w0.y, w0.z, w0.w, w1.x, w1.y, w1.z, w1.w};
  float ba[8] = {b0.x, b0.y, b0.z, b0.w, b1.x, b1.y, b1.z, b1.w};
  float ka[8] = {k0.x, k0.y, k0.z, k0.w, k1.x, k1.y, k1.z, k1.w};
  float va[8] = {v0.x, v0.y, v0.z, v0.w, v1.x, v1.y, v1.z, v1.w};
  float ra[8] = {r0.x, r0.y, r0.z, r0.w, r1.x, r1.y, r1.z, r1.w};

  bf16x8 ok_, ov_, or_;
  float xls[8];
  #pragma unroll
  for (int e = 0; e < 8; e++) {
    float x = (xc[e] - mu) * rstd * wa[e] + ba[e];
    float sx = hasprev ? (xp[e] - mup) * rstdp * wa[e] + ba[e] : 0.f;
    ok_[e] = (__bf16)(sx + ka[e] * (x - sx));
    ov_[e] = (__bf16)(sx + va[e] * (x - sx));
    or_[e] = (__bf16)(sx + ra[e] * (x - sx));
    xls[e] = x;
  }
  size_t obase = (size_t)row * H_ + tid * 8;
  *(bf16x8*)(xk + obase) = ok_;
  *(bf16x8*)(xv + obase) = ov_;
  *(bf16x8*)(xr + obase) = or_;
  if (t == T_ - 1) {
    float* dst = xlast + (size_t)(row >> 11) * H_ + tid * 8;
    #pragma unroll
    for (int e = 0; e < 8; e++) dst[e] = xls[e];
  }
}

// ----------------------- bf16 NT GEMM, 256^2 tile, BK=64, swizzled LDS
// Same geometry/addressing as R5 (verified), NEW schedule: no intra-tile
// barriers, no sched_barrier(0) pinning (m141 lesson), no asm lgkmcnt.
// Per K-tile: {issue 8 stage loads for kt+1 -> ds_read all frags ->
// 64 MFMA -> vmcnt(0) -> s_barrier}.  Compiler free-schedules reads/MFMA
// (it emits fine-grained lgkmcnt itself, m97 evidence).  Buffer safety:
// stages for kt+1 write the buffer last read at kt-1 (fenced by kt-1's end
// barrier); per-wave vmcnt(0)+barrier publishes stages before any read.
// MODE 0: store f32. MODE 1: sigmoid -> bf16. MODE 2: residual add -> f32.
template <int MODE>
__global__ __launch_bounds__(512, 1) void gemm_nt4(
    const __bf16* __restrict__ A, const __bf16* __restrict__ Bw,
    float* __restrict__ outf, __bf16* __restrict__ outb,
    const float* __restrict__ resid) {
  __shared__ __align__(16) char ring[2][65536];   // [buf][A 32K | B 32K]

  // bijective XCD swizzle: 256 blocks, 8 XCDs, chunks of 32 (4 bm-rows x 8 bn)
  const int wgid = blockIdx.x;
  const int lin = (wgid & 7) * 32 + (wgid >> 3);
  const int bm = lin >> 3;          // 0..31  (M/256)
  const int bn = lin & 7;           // 0..7   (N/256)

  const int tid = threadIdx.x;
  const int lane = tid & 63, wv = tid >> 6;
  const int wm = wv >> 2;           // 0..1
  const int wn = wv & 3;            // 0..3
  const int rr = lane & 15, q = lane >> 4;

  f32x4 acc[8][4];
  #pragma unroll
  for (int m = 0; m < 8; m++)
    #pragma unroll
    for (int n = 0; n < 4; n++) acc[m][n] = (f32x4){0.f, 0.f, 0.f, 0.f};

  const char* Ag = (const char*)A + (size_t)(bm * 256) * (H_ * 2);
  const char* Bg = (const char*)Bw + (size_t)(bn * 256) * (H_ * 2);

  // stage addressing: round = 64 rows x 128 B; lane l covers row wv*8+(l>>3),
  // 16-B col (l&7), fetching global col (l&7)^(l>>3)  (inverse swizzle).
  const int srow = wv * 8 + (lane >> 3);
  const int scol = ((lane & 7) ^ (lane >> 3)) << 4;

  // ds_read swizzle: row&7 == rr&7 for all fragment reads.
  const int rsw = rr & 7;

#define STAGE_TILE(kt_, buf_)                                                   \
  {                                                                             \
    char* base_ = ring[buf_];                                                   \
    _Pragma("unroll")                                                           \
    for (int mh_ = 0; mh_ < 2; mh_++) {                                         \
      const char* Mg_ = mh_ ? Bg : Ag;                                          \
      _Pragma("unroll")                                                         \
      for (int hh_ = 0; hh_ < 2; hh_++) {                                       \
        _Pragma("unroll")                                                       \
        for (int rd_ = 0; rd_ < 2; rd_++) {                                     \
          char* dst_ = base_ + mh_ * 32768 + hh_ * 16384 + rd_ * 8192 + wv * 1024; \
          const char* src_ = Mg_ + (size_t)(hh_ * 128 + rd_ * 64 + srow) * (H_ * 2) \
                             + (kt_) * 128 + scol;                              \
          async16(src_, dst_);                                                  \
        }                                                                       \
      }                                                                         \
    }                                                                           \
  }

  // prologue: stage tile 0, drain, barrier.
  STAGE_TILE(0, 0);
  asm volatile("s_waitcnt vmcnt(0)" ::: "memory");
  __builtin_amdgcn_s_barrier();

  for (int kt = 0; kt < NKT_; kt++) {
    const int cur = kt & 1, nxt = cur ^ 1;
    const char* Alds = ring[cur];
    const char* Blds = ring[cur] + 32768;

    // issue next tile's stages first (max slack: ~1 full tile before use)
    if (kt + 1 < NKT_) STAGE_TILE(kt + 1, nxt);

    // B-fragments: read once per tile, held in regs across quadrants
    bf16x8 bfr[4][2];
    #pragma unroll
    for (int ni = 0; ni < 4; ni++)
      #pragma unroll
      for (int ks = 0; ks < 2; ks++) {
        int row_t = wn * 64 + ni * 16 + rr;
        bfr[ni][ks] = *(const bf16x8*)(Blds + row_t * 128 +
                                       (((ks * 4 + q) ^ rsw) << 4));
      }

    #pragma unroll
    for (int p = 0; p < 4; p++) {
      bf16x8 af[2][2];
      #pragma unroll
      for (int mi = 0; mi < 2; mi++)
        #pragma unroll
        for (int ks = 0; ks < 2; ks++) {
          int row_t = wm * 128 + p * 32 + mi * 16 + rr;
          af[mi][ks] = *(const bf16x8*)(Alds + row_t * 128 +
                                        (((ks * 4 + q) ^ rsw) << 4));
        }
      #pragma unroll
      for (int ks = 0; ks < 2; ks++)
        #pragma unroll
        for (int mi = 0; mi < 2; mi++)
          #pragma unroll
          for (int ni = 0; ni < 4; ni++)
            acc[p * 2 + mi][ni] = __builtin_amdgcn_mfma_f32_16x16x32_bf16(
                af[mi][ks], bfr[ni][ks], acc[p * 2 + mi][ni], 0, 0, 0);
    }

    // single tile-boundary sync: own stages published, buffers swappable.
    if (kt + 1 < NKT_) {
      asm volatile("s_waitcnt vmcnt(0)" ::: "memory");
      __builtin_amdgcn_s_barrier();
    }
  }
#undef STAGE_TILE

  // epilogue: acc[m][n] row = bm*256 + wm*128 + m*16 + q*4 + rg, col = bn*256
  // + wn*64 + n*16 + rr.
  const int r0 = bm * 256 + wm * 128 + q * 4;
  const int c0 = bn * 256 + wn * 64 + rr;
  #pragma unroll
  for (int m = 0; m < 8; m++) {
    #pragma unroll
    for (int n = 0; n < 4; n++) {
      int col = c0 + n * 16;
      #pragma unroll
      for (int rg = 0; rg < 4; rg++) {
        int rowg = r0 + m * 16 + rg;
        size_t idx = (size_t)rowg * H_ + col;
        float vv = acc[m][n][rg];
        if (MODE == 0) {
          outf[idx] = vv;
        } else if (MODE == 1) {
          outb[idx] = (__bf16)(1.f / (1.f + __expf(-vv)));
        } else {
          outf[idx] = resid[idx] + vv;
        }
      }
    }
  }
}

// ------------------------------------------------- WKV chunked scan (3 passes)
__global__ __launch_bounds__(256) void wkv_pass1(
    const float* __restrict__ k, const float* __restrict__ v,
    const float* __restrict__ td,
    float* __restrict__ cs_num, float* __restrict__ cs_den,
    float* __restrict__ cs_norm) {
  const int id = blockIdx.x * 256 + threadIdx.x;  // 0..B*H-1
  const int c = blockIdx.y;                       // chunk
  const int b = id >> 11;
  const int hh = id & (H_ - 1);
  const float decay = -__expf(td[hh]);
  float num = 0.f, den = 0.f, norm = -INFINITY;

  const int UN = 16;
  for (int t0 = c * CL_; t0 < (c + 1) * CL_; t0 += UN) {
    float kk[UN], vv[UN];
    size_t base = ((size_t)b * T_ + t0) * H_ + hh;
    #pragma unroll
    for (int i = 0; i < UN; i++) {
      kk[i] = k[base + (size_t)i * H_];
      vv[i] = v[base + (size_t)i * H_];
    }
    #pragma unroll
    for (int i = 0; i < UN; i++) {
      float dpn = decay + norm;
      float nn = fmaxf(dpn, kk[i]);
      float ed = __expf(dpn - nn), ek = __expf(kk[i] - nn);
      num = ed * num + ek * vv[i];
      den = ed * den + ek;
      norm = nn;
    }
  }
  cs_num[c * BH_ + id] = num;
  cs_den[c * BH_ + id] = den;
  cs_norm[c * BH_ + id] = norm;
}

__global__ __launch_bounds__(256) void wkv_scan(
    const float* __restrict__ cs_num, const float* __restrict__ cs_den,
    const float* __restrict__ cs_norm, const float* __restrict__ td,
    float* __restrict__ px_num, float* __restrict__ px_den,
    float* __restrict__ px_norm) {
  const int id = blockIdx.x * 256 + threadIdx.x;  // 0..B*H-1
  const int hh = id & (H_ - 1);
  const float Lw = -__expf(td[hh]) * (float)CL_;  // CL_ * decay
  float num = 0.f, den = 0.f, norm = -INFINITY;
  for (int c = 0; c < CH_; c++) {
    px_num[c * BH_ + id] = num;
    px_den[c * BH_ + id] = den;
    px_norm[c * BH_ + id] = norm;
    float n_c = cs_num[c * BH_ + id];
    float d_c = cs_den[c * BH_ + id];
    float m_c = cs_norm[c * BH_ + id];
    float sn = norm + Lw;                 // shifted incoming norm
    float on = fmaxf(sn, m_c);            // m_c is always finite
    float ea = __expf(sn - on), eb = __expf(m_c - on);
    num = ea * num + eb * n_c;
    den = ea * den + eb * d_c;
    norm = on;
  }
}

__global__ __launch_bounds__(256) void wkv_pass2(
    const float* __restrict__ k, const float* __restrict__ v,
    const __bf16* __restrict__ r, const float* __restrict__ td,
    const float* __restrict__ cw,
    const float* __restrict__ px_num, const float* __restrict__ px_den,
    const float* __restrict__ px_norm,
    __bf16* __restrict__ a, float* __restrict__ ndn) {
  const int id = blockIdx.x * 256 + threadIdx.x;  // 0..B*H-1
  const int c = blockIdx.y;
  const int b = id >> 11;
  const int hh = id & (H_ - 1);
  const float decay = -__expf(td[hh]);
  const float cwv = cw[hh];
  float num = px_num[c * BH_ + id];
  float den = px_den[c * BH_ + id];
  float norm = px_norm[c * BH_ + id];

  const int UN = 16;
  for (int t0 = c * CL_; t0 < (c + 1) * CL_; t0 += UN) {
    float kk[UN], vv[UN], rrv[UN];
    size_t base = ((size_t)b * T_ + t0) * H_ + hh;
    #pragma unroll
    for (int i = 0; i < UN; i++) {
      kk[i] = k[base + (size_t)i * H_];
      vv[i] = v[base + (size_t)i * H_];
      rrv[i] = (float)r[base + (size_t)i * H_];
    }
    #pragma unroll
    for (int i = 0; i < UN; i++) {
      float kt = kk[i], vt = vv[i];
      float ct = cwv + kt;
      float cn = fmaxf(ct, norm);
      float ep = __expf(norm - cn), ec = __expf(ct - cn);
      float o = (ep * num + ec * vt) / (ep * den + ec);
      a[base + (size_t)i * H_] = (__bf16)(rrv[i] * o);
      float dpn = decay + norm;
      float nn = fmaxf(dpn, kt);
      float ed = __expf(dpn - nn), ek = __expf(kt - nn);
      num = ed * num + ek * vt;
      den = ed * den + ek;
      norm = nn;
    }
  }
  if (c == CH_ - 1) {
    ndn[id] = num;
    ndn[BH_ + id] = den;
    ndn[2 * BH_ + id] = norm;
  }
}

// ----------------------------------------------------------------------- host
extern "C" void kernel_launch(void* const* d_in, const int* in_sizes, int n_in,
                              void* d_out, int out_size, void* d_ws, size_t ws_size,
                              hipStream_t stream) {
  const float* h   = (const float*)d_in[0];
  const float* lnw = (const float*)d_in[1];
  const float* lnb = (const float*)d_in[2];
  const float* Wk  = (const float*)d_in[3];
  const float* Wv  = (const float*)d_in[4];
  const float* Wr  = (const float*)d_in[5];
  const float* Wo  = (const float*)d_in[6];
  const float* mk  = (const float*)d_in[7];
  const float* mv  = (const float*)d_in[8];
  const float* mr  = (const float*)d_in[9];
  const float* td  = (const float*)d_in[10];
  const float* cw  = (const float*)d_in[11];

  char* ws = (char*)d_ws;
  const size_t MB = 1048576;
  // 256 MB workspace layout:
  //   [0,32)    xk   (bf16, later reused as 'a' = r*wkv)
  //   [32,64)   xv   (bf16, later reused as 'r')
  //   [64,96)   xr   (bf16; dead after r-GEMM -> scan state lives here)
  //   [96,160)  kbuf (f32)
  //   [160,224) vbuf (f32)
  //   [224,256) Wk16/Wv16/Wr16/Wo16 (bf16, 8 MB each)
  __bf16* xk   = (__bf16*)(ws);
  __bf16* xv   = (__bf16*)(ws + 32 * MB);
  __bf16* xr   = (__bf16*)(ws + 64 * MB);
  float*  kbuf = (float*)(ws + 96 * MB);
  float*  vbuf = (float*)(ws + 160 * MB);
  __bf16* Wk16 = (__bf16*)(ws + 224 * MB);
  __bf16* Wv16 = Wk16 + (size_t)H_ * H_;
  __bf16* Wr16 = Wv16 + (size_t)H_ * H_;
  __bf16* Wo16 = Wr16 + (size_t)H_ * H_;
  float* cs_num  = (float*)(ws + 64 * MB);
  float* cs_den  = cs_num + (size_t)CH_ * BH_;
  float* cs_norm = cs_den + (size_t)CH_ * BH_;
  float* px_num  = cs_norm + (size_t)CH_ * BH_;
  float* px_den  = px_num + (size_t)CH_ * BH_;
  float* px_norm = px_den + (size_t)CH_ * BH_;

  float* out  = (float*)d_out;
  float* xlast = out + (size_t)BT_ * H_;
  float* ndn   = xlast + (size_t)B_ * H_;

  const int cvt_blocks = (H_ * H_) / (256 * 8);
  cvt_bf16_kernel<<<cvt_blocks, 256, 0, stream>>>(Wk, Wk16);
  cvt_bf16_kernel<<<cvt_blocks, 256, 0, stream>>>(Wv, Wv16);
  cvt_bf16_kernel<<<cvt_blocks, 256, 0, stream>>>(Wr, Wr16);
  cvt_bf16_kernel<<<cvt_blocks, 256, 0, stream>>>(Wo, Wo16);

  ln_mix_kernel<<<BT_, 256, 0, stream>>>(h, lnw, lnb, mk, mv, mr, xk, xv, xr, xlast);

  const int gemm_blocks = (BT_ / 256) * (H_ / 256);  // 32 * 8 = 256
  gemm_nt4<0><<<gemm_blocks, 512, 0, stream>>>(xk, Wk16, kbuf, nullptr, nullptr);
  gemm_nt4<0><<<gemm_blocks, 512, 0, stream>>>(xv, Wv16, vbuf, nullptr, nullptr);
  gemm_nt4<1><<<gemm_blocks, 512, 0, stream>>>(xr, Wr16, nullptr, xv /* r reuses xv */, nullptr);

  dim3 wg(BH_ / 256, CH_);
  wkv_pass1<<<wg, 256, 0, stream>>>(kbuf, vbuf, td, cs_num, cs_den, cs_norm);
  wkv_scan<<<BH_ / 256, 256, 0, stream>>>(cs_num, cs_den, cs_norm, td,
                                          px_num, px_den, px_norm);
  wkv_pass2<<<wg, 256, 0, stream>>>(kbuf, vbuf, xv, td, cw,
                                    px_num, px_den, px_norm,
                                    xk /* a reuses xk */, ndn);

  gemm_nt4<2><<<gemm_blocks, 512, 0, stream>>>(xk, Wo16, out, nullptr, h);
}